// Round 1
// baseline (995.442 us; speedup 1.0000x reference)
//
#include <hip/hip_runtime.h>
#include <math.h>

#define NB   64
#define T0   1024
#define CIN  128
#define HID  256
#define TGT  128
#define PRED 192
#define NROWS (NB*CIN)   // 8192 rows per scale for the spectrum mean

// ---------------- workspace layout (float offsets) ----------------
// xct  [64][128][1024]           f32
// s1   [64][128][512]
// s2   [64][128][256]
// P0   [1024 blocks][520]  per-block partial |X| sums, scale0 (513 used)
// P1   [1024][264]  (257 used)
// P2   [1024][136]  (129 used)
// AMPS [1024]  : a0@0(513), a1@520(257), a2@780(129)
// META [64]    : freqs int[9] @0, wk float[9] @16, sw float[3] @32
// FUSED[64][256][1024]  (reused per scale, row stride = t)
// PREDB[64][192][256]
static const size_t XCT_OFF   = 0;
static const size_t S1_OFF    = 8388608;
static const size_t S2_OFF    = 12582912;
static const size_t P0_OFF    = 14680064;
static const size_t P1_OFF    = 15212544;
static const size_t P2_OFF    = 15482880;
static const size_t AMPS_OFF  = 15622144;
static const size_t META_OFF  = 15623168;
static const size_t FUSED_OFF = 15623232;
static const size_t PREDB_OFF = 32400448;
// end = 35,546,176 floats = 142.2 MB

// ---------------- transpose x[B,T,C] -> xct[B,C,T] ----------------
__global__ __launch_bounds__(256) void transpose_x(const float* __restrict__ x,
                                                   float* __restrict__ xct) {
    __shared__ float tile[32][33];
    int b = blockIdx.z;
    int t0 = blockIdx.x * 32, c0 = blockIdx.y * 32;
    int tx = threadIdx.x, ty = threadIdx.y;       // 32 x 8
#pragma unroll
    for (int i = 0; i < 4; i++) {
        int t = t0 + ty + i * 8, c = c0 + tx;
        tile[ty + i * 8][tx] = x[((size_t)b * T0 + t) * CIN + c];
    }
    __syncthreads();
#pragma unroll
    for (int i = 0; i < 4; i++) {
        int c = c0 + ty + i * 8, t = t0 + tx;
        xct[((size_t)b * CIN + c) * T0 + t] = tile[tx][ty + i * 8];
    }
}

// ---------------- stride-2 average pool over last axis ----------------
template<int LOGOUT>
__global__ __launch_bounds__(256) void pool2(const float* __restrict__ in,
                                             float* __restrict__ out, int n_out) {
    const int tmask = (1 << LOGOUT) - 1;
    for (int idx = blockIdx.x * 256 + threadIdx.x; idx < n_out; idx += gridDim.x * 256) {
        int row = idx >> LOGOUT;
        int jj  = idx & tmask;
        const float* r = in + (((size_t)row) << (LOGOUT + 1));
        out[idx] = 0.5f * (r[2 * jj] + r[2 * jj + 1]);
    }
}

// ---------------- radix-2 FFT per row, accumulate |X| over 8 rows ----------------
template<int LOGT>
__global__ __launch_bounds__(256) void fft_amps(const float* __restrict__ xm,
                                                float* __restrict__ part, int pad) {
    constexpr int T = 1 << LOGT;
    constexpr int F = T / 2;                        // bins 0..F (rfft)
    __shared__ float re[T], im[T];
    __shared__ float twc[F], tws[F];
    __shared__ float acc[F + 1];
    int tid = threadIdx.x;
    for (int j = tid; j < F; j += 256) {
        float s, c;
        sincosf(-6.283185307179586f * (float)j / (float)T, &s, &c);
        twc[j] = c; tws[j] = s;
    }
    for (int i = tid; i <= F; i += 256) acc[i] = 0.f;
    __syncthreads();

    int rowbase = blockIdx.x * 8;
    for (int rr = 0; rr < 8; rr++) {
        const float* row = xm + (size_t)(rowbase + rr) * T;
        for (int j = tid; j < T; j += 256) {        // bit-reversed load (DIT)
            int rv = (int)(__brev((unsigned)j) >> (32 - LOGT));
            re[rv] = row[j];
            im[rv] = 0.f;
        }
        __syncthreads();
        for (int s = 1; s <= LOGT; s++) {
            int mh = 1 << (s - 1);
            for (int bf = tid; bf < T / 2; bf += 256) {
                int k  = bf & (mh - 1);
                int g  = bf >> (s - 1);
                int i1 = (g << s) + k;
                int i2 = i1 + mh;
                int twi = k << (LOGT - s);
                float wr = twc[twi], wi = tws[twi];
                float xr = re[i2], xi = im[i2];
                float tr = wr * xr - wi * xi;
                float ti = wr * xi + wi * xr;
                float ur = re[i1], ui = im[i1];
                re[i1] = ur + tr; im[i1] = ui + ti;
                re[i2] = ur - tr; im[i2] = ui - ti;
            }
            __syncthreads();
        }
        for (int f = tid; f <= F; f += 256)
            if (f >= 1) acc[f] += sqrtf(re[f] * re[f] + im[f] * im[f]);
        __syncthreads();                             // protect re/im before next load
    }
    for (int f = tid; f <= F; f += 256)
        part[(size_t)blockIdx.x * pad + f] = acc[f]; // acc[0] stays 0
}

// ---------------- deterministic reduce of partials -> amps (mean) ----------------
__global__ __launch_bounds__(256) void reduce_amps(const float* __restrict__ parts,
                                                   float* __restrict__ amps) {
    const int PADs[3] = {520, 264, 136};
    const int Fs[3]   = {513, 257, 129};
    const size_t POFF[3] = {0, (size_t)1024 * 520, (size_t)1024 * 520 + (size_t)1024 * 264};
    const int AOFF[3] = {0, 520, 780};
    int s  = blockIdx.y;
    int fl = threadIdx.x & 63;
    int rg = threadIdx.x >> 6;                       // 0..3
    int f  = blockIdx.x * 64 + fl;
    bool valid = f < Fs[s];
    const float* base = parts + POFF[s];
    int pad = PADs[s];
    float sum = 0.f;
    if (valid)
        for (int r = rg; r < 1024; r += 4) sum += base[(size_t)r * pad + f];
    __shared__ float red[256];
    red[threadIdx.x] = sum;
    __syncthreads();
    if (rg == 0 && valid) {
        float tot = red[fl] + red[fl + 64] + red[fl + 128] + red[fl + 192];
        amps[AOFF[s] + f] = tot * (1.f / 8192.f);
    }
}

// ---------------- top-3 freqs + softmax weights (serial, deterministic) ----------------
__global__ void meta_topk(const float* __restrict__ amps, const float* __restrict__ slog,
                          int* __restrict__ freqs, float* __restrict__ wk,
                          float* __restrict__ sw) {
    if (threadIdx.x != 0) return;
    const int offs[3] = {0, 520, 780};
    const int Fs[3]   = {513, 257, 129};
    for (int m = 0; m < 3; m++) {
        const float* a = amps + offs[m];
        int F = Fs[m];
        int   c0 = -1, c1 = -1, c2 = -1;
        float b0 = -1.f, b1 = -1.f, b2 = -1.f;
        for (int i = 0; i < F; i++) {                // stable top-3, strict >
            float v = a[i];
            if (v > b0)      { b2 = b1; c2 = c1; b1 = b0; c1 = c0; b0 = v; c0 = i; }
            else if (v > b1) { b2 = b1; c2 = c1; b1 = v; c1 = i; }
            else if (v > b2) { b2 = v; c2 = i; }
        }
        int fr[3] = {max(1, c0), max(1, c1), max(1, c2)};
        float av[3] = {a[fr[0]], a[fr[1]], a[fr[2]]};
        float mx = fmaxf(av[0], fmaxf(av[1], av[2]));
        float e0 = expf(av[0] - mx), e1 = expf(av[1] - mx), e2 = expf(av[2] - mx);
        float inv = 1.f / (e0 + e1 + e2);
        freqs[m * 3 + 0] = fr[0]; freqs[m * 3 + 1] = fr[1]; freqs[m * 3 + 2] = fr[2];
        wk[m * 3 + 0] = e0 * inv; wk[m * 3 + 1] = e1 * inv; wk[m * 3 + 2] = e2 * inv;
    }
    float s0 = slog[0], s1 = slog[1], s2 = slog[2];
    float mx = fmaxf(s0, fmaxf(s1, s2));
    float e0 = expf(s0 - mx), e1 = expf(s1 - mx), e2 = expf(s2 - mx);
    float inv = 3.f / (e0 + e1 + e2);
    sw[0] = e0 * inv; sw[1] = e1 * inv; sw[2] = e2 * inv;
}

// ---------------- out = residual slice of x ----------------
__global__ __launch_bounds__(256) void out_init(const float* __restrict__ x,
                                                float* __restrict__ out) {
    const int n = NB * PRED * TGT;
    for (int idx = blockIdx.x * 256 + threadIdx.x; idx < n; idx += gridDim.x * 256) {
        int b = idx / (PRED * TGT);
        int rem = idx - b * (PRED * TGT);
        out[idx] = x[(size_t)b * T0 * CIN + (size_t)(T0 - PRED) * CIN + rem];
    }
}

// ---------------- fused: (sum_k wk * depthwise_k) -> pointwise 128->256 ----------------
// fused[b][h][l] = pw_b[h] + sum_c pw_w[h][c] * ( dw_b[c] + sum_k wk_k * dwconv_k(c,l) )
template<int T>
__global__ __launch_bounds__(256) void conv_fused_k(const float* __restrict__ xm,
        const float* __restrict__ dw_w, const float* __restrict__ dw_b,
        const float* __restrict__ pw_w, const float* __restrict__ pw_b,
        const int* __restrict__ freqs, const float* __restrict__ wkbuf, int m,
        float* __restrict__ fused) {
    __shared__ __align__(16) float dwacc[CIN * 32];  // [c][j], rows 128B aligned
    __shared__ float pwT[HID * 33];                  // staged pw chunk [h][cc], pad 33
    int tid = threadIdx.x;
    int b = blockIdx.y;
    int tile0 = blockIdx.x * 32;
    int j = tid & 31, cg = tid >> 5;                 // j: position lane, cg: channel group
    int l = tile0 + j;

    // phase 1: 9-tap geometry for the 3 freqs (position-only, channel-independent)
    int   posv[27];
    float okw[27];
#pragma unroll
    for (int k = 0; k < 3; k++) {
        int   f   = freqs[m * 3 + k];
        float wkv = wkbuf[m * 3 + k];
        int p    = T / f;
        int rows = (T + p - 1) / p;
        int r  = l / p;
        int cc = l - r * p;
        int q = k * 9;
#pragma unroll
        for (int dr = -1; dr <= 1; dr++) {
#pragma unroll
            for (int dc = -1; dc <= 1; dc++) {
                int rr2 = r + dr, c2 = cc + dc;
                int pos = rr2 * p + c2;
                bool ok = (rr2 >= 0) && (rr2 < rows) && (c2 >= 0) && (c2 < p) && (pos < T);
                posv[q] = ok ? pos : 0;
                okw[q]  = ok ? wkv : 0.f;
                q++;
            }
        }
    }
#pragma unroll
    for (int i = 0; i < 16; i++) {
        int c = cg + i * 8;
        const float* xr = xm + ((size_t)b * CIN + c) * T;
        const float* w9 = dw_w + c * 9;
        float s = 0.f;
#pragma unroll
        for (int q = 0; q < 9; q++) {
            float tmp = okw[q]      * xr[posv[q]]
                      + okw[9 + q]  * xr[posv[9 + q]]
                      + okw[18 + q] * xr[posv[18 + q]];
            s += w9[q] * tmp;
        }
        dwacc[c * 32 + j] = s + dw_b[c];
    }

    // phase 2: pointwise GEMM, h = tid, 32 positions per thread
    float acc[32];
    float pb = pw_b[tid];
#pragma unroll
    for (int jj = 0; jj < 32; jj++) acc[jj] = pb;
    for (int c0 = 0; c0 < CIN; c0 += 32) {
        __syncthreads();                             // also orders phase1 -> phase2
#pragma unroll
        for (int i = 0; i < 32; i++) {
            int e = i * 256 + tid;                   // 8192 = 256h x 32c
            int hh = e >> 5, ccc = e & 31;
            pwT[hh * 33 + ccc] = pw_w[hh * CIN + c0 + ccc];
        }
        __syncthreads();
        for (int ccc = 0; ccc < 32; ccc++) {
            float pv = pwT[tid * 33 + ccc];          // conflict-free (stride 33)
            const float* dRow = &dwacc[(c0 + ccc) * 32];
#pragma unroll
            for (int jj = 0; jj < 32; jj++) acc[jj] += pv * dRow[jj];  // b128 broadcasts
        }
    }
    size_t ob = ((size_t)b * HID + tid) * T + tile0;
#pragma unroll
    for (int jj = 0; jj < 32; jj++) fused[ob + jj] = acc[jj];
}

// ---------------- time projection: pred[b][p][h] = b_t[p] + sum_l fused[b][h][l]*w_t[p][l]
template<int T>
__global__ __launch_bounds__(256) void timeproj(const float* __restrict__ fused,
        const float* __restrict__ w_t, const float* __restrict__ b_t,
        float* __restrict__ pred) {
    __shared__ float wtS[32 * 33];                   // [p][kk]
    __shared__ float fuS[128 * 33];                  // [h][kk]
    int tid = threadIdx.x;
    int p0 = blockIdx.x * 32;
    int h0 = blockIdx.y * 128;
    int b  = blockIdx.z;
    int rg = tid >> 5;                               // 0..7 -> 4 p's each
    int ln = tid & 31;                               // -> 4 h's each (interleaved by 32)
    float acc[4][4];
#pragma unroll
    for (int i = 0; i < 4; i++)
#pragma unroll
        for (int jj = 0; jj < 4; jj++) acc[i][jj] = 0.f;

    for (int k0 = 0; k0 < T; k0 += 32) {
        __syncthreads();
#pragma unroll
        for (int i = 0; i < 4; i++) {
            int ee = i * 256 + tid;                  // 1024 = 32p x 32k
            int p = ee >> 5, kk = ee & 31;
            wtS[p * 33 + kk] = w_t[(size_t)(p0 + p) * T + k0 + kk];
        }
#pragma unroll
        for (int i = 0; i < 16; i++) {
            int ee = i * 256 + tid;                  // 4096 = 128h x 32k
            int h = ee >> 5, kk = ee & 31;
            fuS[h * 33 + kk] = fused[((size_t)b * HID + h0 + h) * T + k0 + kk];
        }
        __syncthreads();
        for (int kk = 0; kk < 32; kk++) {
            float wv[4], fv[4];
#pragma unroll
            for (int i = 0; i < 4; i++) wv[i] = wtS[(rg * 4 + i) * 33 + kk];   // broadcast
#pragma unroll
            for (int jj = 0; jj < 4; jj++) fv[jj] = fuS[(ln + 32 * jj) * 33 + kk]; // conflict-free
#pragma unroll
            for (int i = 0; i < 4; i++)
#pragma unroll
                for (int jj = 0; jj < 4; jj++) acc[i][jj] += wv[i] * fv[jj];
        }
    }
#pragma unroll
    for (int i = 0; i < 4; i++) {
        int p = p0 + rg * 4 + i;
        float bt = b_t[p];
#pragma unroll
        for (int jj = 0; jj < 4; jj++) {
            int h = h0 + ln + 32 * jj;
            pred[((size_t)b * PRED + p) * HID + h] = acc[i][jj] + bt;
        }
    }
}

// ---------------- channel projection + weighted accumulate into out ----------------
__global__ __launch_bounds__(256) void chproj8(const float* __restrict__ pred,
        const float* __restrict__ w_ch, const float* __restrict__ b_ch,
        const float* __restrict__ swbuf, int m, float* __restrict__ out) {
    __shared__ __align__(16) float prS[8 * HID];
    int tid = threadIdx.x;
    int bp0 = blockIdx.x * 8;                        // 8 (b,p) rows per block
#pragma unroll
    for (int i = 0; i < 8; i++) {
        int e = i * 256 + tid;                       // 2048
        prS[e] = pred[(size_t)bp0 * HID + e];
    }
    __syncthreads();
    int o = tid & 127, g = tid >> 7;                 // two groups of 128 o-lanes
    float swv = swbuf[m], bc = b_ch[o];
    const float4* w4  = (const float4*)(w_ch + (size_t)o * HID);
    const float4* pr4 = (const float4*)prS;
    float a0 = 0.f, a1 = 0.f, a2 = 0.f, a3 = 0.f;
    for (int i = 0; i < HID / 4; i++) {
        float4 w  = w4[i];
        float4 q0 = pr4[(g * 4 + 0) * (HID / 4) + i];
        float4 q1 = pr4[(g * 4 + 1) * (HID / 4) + i];
        float4 q2 = pr4[(g * 4 + 2) * (HID / 4) + i];
        float4 q3 = pr4[(g * 4 + 3) * (HID / 4) + i];
        a0 += w.x * q0.x + w.y * q0.y + w.z * q0.z + w.w * q0.w;
        a1 += w.x * q1.x + w.y * q1.y + w.z * q1.z + w.w * q1.w;
        a2 += w.x * q2.x + w.y * q2.y + w.z * q2.z + w.w * q2.w;
        a3 += w.x * q3.x + w.y * q3.y + w.z * q3.z + w.w * q3.w;
    }
    size_t ob = (size_t)bp0 * TGT;
    out[ob + (g * 4 + 0) * TGT + o] += swv * (bc + a0);
    out[ob + (g * 4 + 1) * TGT + o] += swv * (bc + a1);
    out[ob + (g * 4 + 2) * TGT + o] += swv * (bc + a2);
    out[ob + (g * 4 + 3) * TGT + o] += swv * (bc + a3);
}

extern "C" void kernel_launch(void* const* d_in, const int* in_sizes, int n_in,
                              void* d_out, int out_size, void* d_ws, size_t ws_size,
                              hipStream_t stream) {
    const float* x    = (const float*)d_in[0];
    const float* dw_w = (const float*)d_in[1];
    const float* dw_b = (const float*)d_in[2];
    const float* pw_w = (const float*)d_in[3];
    const float* pw_b = (const float*)d_in[4];
    const float* wt0  = (const float*)d_in[5];
    const float* bt0  = (const float*)d_in[6];
    const float* wt1  = (const float*)d_in[7];
    const float* bt1  = (const float*)d_in[8];
    const float* wt2  = (const float*)d_in[9];
    const float* bt2  = (const float*)d_in[10];
    const float* w_ch = (const float*)d_in[11];
    const float* b_ch = (const float*)d_in[12];
    const float* slog = (const float*)d_in[13];
    float* out = (float*)d_out;
    float* ws  = (float*)d_ws;

    float* xct   = ws + XCT_OFF;
    float* s1b   = ws + S1_OFF;
    float* s2b   = ws + S2_OFF;
    float* parts = ws + P0_OFF;                      // P0,P1,P2 contiguous
    float* ampsb = ws + AMPS_OFF;
    int*   freqs = (int*)(ws + META_OFF);
    float* wkb   = ws + META_OFF + 16;
    float* swb   = ws + META_OFF + 32;
    float* fusedb= ws + FUSED_OFF;
    float* predb = ws + PREDB_OFF;

    transpose_x<<<dim3(32, 4, NB), dim3(32, 8, 1), 0, stream>>>(x, xct);
    pool2<9><<<2048, 256, 0, stream>>>(xct, s1b, NROWS * 512);
    pool2<8><<<1024, 256, 0, stream>>>(s1b, s2b, NROWS * 256);

    fft_amps<10><<<1024, 256, 0, stream>>>(xct, parts, 520);
    fft_amps<9><<<1024, 256, 0, stream>>>(s1b, parts + (size_t)1024 * 520, 264);
    fft_amps<8><<<1024, 256, 0, stream>>>(s2b, parts + (size_t)1024 * 520 + (size_t)1024 * 264, 136);
    reduce_amps<<<dim3(9, 3), 256, 0, stream>>>(parts, ampsb);
    meta_topk<<<1, 64, 0, stream>>>(ampsb, slog, freqs, wkb, swb);

    out_init<<<1024, 256, 0, stream>>>(x, out);

    // scale 0 (T=1024)
    conv_fused_k<1024><<<dim3(32, NB), 256, 0, stream>>>(xct, dw_w, dw_b, pw_w, pw_b,
                                                         freqs, wkb, 0, fusedb);
    timeproj<1024><<<dim3(6, 2, NB), 256, 0, stream>>>(fusedb, wt0, bt0, predb);
    chproj8<<<NB * PRED / 8, 256, 0, stream>>>(predb, w_ch, b_ch, swb, 0, out);

    // scale 1 (T=512)
    conv_fused_k<512><<<dim3(16, NB), 256, 0, stream>>>(s1b, dw_w, dw_b, pw_w, pw_b,
                                                        freqs, wkb, 1, fusedb);
    timeproj<512><<<dim3(6, 2, NB), 256, 0, stream>>>(fusedb, wt1, bt1, predb);
    chproj8<<<NB * PRED / 8, 256, 0, stream>>>(predb, w_ch, b_ch, swb, 1, out);

    // scale 2 (T=256)
    conv_fused_k<256><<<dim3(8, NB), 256, 0, stream>>>(s2b, dw_w, dw_b, pw_w, pw_b,
                                                       freqs, wkb, 2, fusedb);
    timeproj<256><<<dim3(6, 2, NB), 256, 0, stream>>>(fusedb, wt2, bt2, predb);
    chproj8<<<NB * PRED / 8, 256, 0, stream>>>(predb, w_ch, b_ch, swb, 2, out);
}

// Round 2
// 577.850 us; speedup vs baseline: 1.7227x; 1.7227x over previous
//
#include <hip/hip_runtime.h>
#include <math.h>

#define NB   64
#define T0   1024
#define CIN  128
#define HID  256
#define TGT  128
#define PRED 192
#define NROWS (NB*CIN)

typedef __attribute__((ext_vector_type(4))) float f32x4;
typedef __attribute__((ext_vector_type(8))) short s16x8;

// ---------------- workspace layout (float offsets) ----------------
static const size_t XCT_OFF   = 0;          // [64][128][1024] f32
static const size_t S1_OFF    = 8388608;    // [64][128][512]
static const size_t S2_OFF    = 12582912;   // [64][128][256]
static const size_t P0_OFF    = 14680064;   // [1024][520]
static const size_t P1_OFF    = 15212544;   // [1024][264]
static const size_t P2_OFF    = 15482880;   // [1024][136]
static const size_t AMPS_OFF  = 15622144;   // 1024
static const size_t META_OFF  = 15623168;   // 64: freqs int[9]@0, wk f32[9]@16, sw f32[3]@32
static const size_t W2T_OFF   = 15623232;   // [128 c][128 o] bf16 stored in 8192 floats; use 16384 to be safe
static const size_t PBS_OFF   = 15639616;   // Pb[128], S_ch[128] f32
static const size_t WSUM_OFF  = 15639872;   // [3][192] f32
static const size_t WTB_OFF   = 15640448;   // bf16 w_t: 192*(1024+512+256)=344064 ushorts = 172032 floats
static const size_t DWMIX_OFF = 15812480;   // bf16 [64*128][1024] = 8388608 ushorts = 4194304 floats
static const size_t TP_OFF    = 20006784;   // bf16 [3][192][8192] = 4718592 ushorts = 2359296 floats
// end = 22366080 floats = 89.5 MB

__device__ inline unsigned short f2bf(float x) {
    union { float f; unsigned u; } v; v.f = x;
    unsigned r = (v.u + 0x7FFFu + ((v.u >> 16) & 1u)) >> 16;
    return (unsigned short)r;
}
__device__ inline float bf2f(unsigned short u) {
    union { unsigned u; float f; } v; v.u = ((unsigned)u) << 16;
    return v.f;
}

// ---------------- transpose x[B,T,C] -> xct[B,C,T] ----------------
__global__ __launch_bounds__(256) void transpose_x(const float* __restrict__ x,
                                                   float* __restrict__ xct) {
    __shared__ float tile[32][33];
    int b = blockIdx.z;
    int t0 = blockIdx.x * 32, c0 = blockIdx.y * 32;
    int tx = threadIdx.x, ty = threadIdx.y;
#pragma unroll
    for (int i = 0; i < 4; i++) {
        int t = t0 + ty + i * 8, c = c0 + tx;
        tile[ty + i * 8][tx] = x[((size_t)b * T0 + t) * CIN + c];
    }
    __syncthreads();
#pragma unroll
    for (int i = 0; i < 4; i++) {
        int c = c0 + ty + i * 8, t = t0 + tx;
        xct[((size_t)b * CIN + c) * T0 + t] = tile[tx][ty + i * 8];
    }
}

// ---------------- stride-2 average pool ----------------
template<int LOGOUT>
__global__ __launch_bounds__(256) void pool2(const float* __restrict__ in,
                                             float* __restrict__ out, int n_out) {
    const int tmask = (1 << LOGOUT) - 1;
    for (int idx = blockIdx.x * 256 + threadIdx.x; idx < n_out; idx += gridDim.x * 256) {
        int row = idx >> LOGOUT;
        int jj  = idx & tmask;
        const float* r = in + (((size_t)row) << (LOGOUT + 1));
        out[idx] = 0.5f * (r[2 * jj] + r[2 * jj + 1]);
    }
}

// ---------------- FFT: 2 real rows packed per complex FFT, 8 rows/block ----------------
template<int LOGT>
__global__ __launch_bounds__(256) void fft_amps(const float* __restrict__ xm,
                                                float* __restrict__ part, int pad) {
    constexpr int T = 1 << LOGT;
    constexpr int F = T / 2;
    __shared__ float re[T], im[T];
    __shared__ float twc[F], tws[F];
    __shared__ float acc[F + 1];
    int tid = threadIdx.x;
    for (int j = tid; j < F; j += 256) {
        float s, c;
        sincosf(-6.283185307179586f * (float)j / (float)T, &s, &c);
        twc[j] = c; tws[j] = s;
    }
    for (int i = tid; i <= F; i += 256) acc[i] = 0.f;
    __syncthreads();

    int rowbase = blockIdx.x * 8;
    for (int pr = 0; pr < 4; pr++) {
        const float* row0 = xm + (size_t)(rowbase + 2 * pr) * T;
        const float* row1 = row0 + T;                 // rows contiguous
        for (int j = tid; j < T; j += 256) {          // bit-reversed load (DIT)
            int rv = (int)(__brev((unsigned)j) >> (32 - LOGT));
            re[rv] = row0[j];
            im[rv] = row1[j];
        }
        __syncthreads();
        for (int s = 1; s <= LOGT; s++) {
            int mh = 1 << (s - 1);
            for (int bf = tid; bf < T / 2; bf += 256) {
                int k  = bf & (mh - 1);
                int g  = bf >> (s - 1);
                int i1 = (g << s) + k;
                int i2 = i1 + mh;
                int twi = k << (LOGT - s);
                float wr = twc[twi], wi = tws[twi];
                float xr = re[i2], xi = im[i2];
                float tr = wr * xr - wi * xi;
                float ti = wr * xi + wi * xr;
                float ur = re[i1], ui = im[i1];
                re[i1] = ur + tr; im[i1] = ui + ti;
                re[i2] = ur - tr; im[i2] = ui - ti;
            }
            __syncthreads();
        }
        // unpack two real spectra: X0=(Z(f)+conj(Z(T-f)))/2, X1=(Z(f)-conj(Z(T-f)))/(2i)
        for (int f = tid; f <= F; f += 256) {
            if (f >= 1) {
                int mf = T - f;
                float rf = re[f], imf = im[f];
                float rm = re[mf], imm = im[mf];
                float m0 = sqrtf((rf + rm) * (rf + rm) + (imf - imm) * (imf - imm));
                float m1 = sqrtf((imf + imm) * (imf + imm) + (rf - rm) * (rf - rm));
                acc[f] += 0.5f * (m0 + m1);
            }
        }
        __syncthreads();
    }
    for (int f = tid; f <= F; f += 256)
        part[(size_t)blockIdx.x * pad + f] = acc[f];
}

// ---------------- deterministic reduce of partials -> amps (mean) ----------------
__global__ __launch_bounds__(256) void reduce_amps(const float* __restrict__ parts,
                                                   float* __restrict__ amps) {
    const int PADs[3] = {520, 264, 136};
    const int Fs[3]   = {513, 257, 129};
    const size_t POFF[3] = {0, (size_t)1024 * 520, (size_t)1024 * 520 + (size_t)1024 * 264};
    const int AOFF[3] = {0, 520, 780};
    int s  = blockIdx.y;
    int fl = threadIdx.x & 63;
    int rg = threadIdx.x >> 6;
    int f  = blockIdx.x * 64 + fl;
    bool valid = f < Fs[s];
    const float* base = parts + POFF[s];
    int pad = PADs[s];
    float sum = 0.f;
    if (valid)
        for (int r = rg; r < 1024; r += 4) sum += base[(size_t)r * pad + f];
    __shared__ float red[256];
    red[threadIdx.x] = sum;
    __syncthreads();
    if (rg == 0 && valid) {
        float tot = red[fl] + red[fl + 64] + red[fl + 128] + red[fl + 192];
        amps[AOFF[s] + f] = tot * (1.f / 8192.f);
    }
}

// ---------------- top-3 freqs + softmax weights ----------------
__global__ void meta_topk(const float* __restrict__ amps, const float* __restrict__ slog,
                          int* __restrict__ freqs, float* __restrict__ wk,
                          float* __restrict__ sw) {
    if (threadIdx.x != 0) return;
    const int offs[3] = {0, 520, 780};
    const int Fs[3]   = {513, 257, 129};
    for (int m = 0; m < 3; m++) {
        const float* a = amps + offs[m];
        int F = Fs[m];
        int   c0 = -1, c1 = -1, c2 = -1;
        float b0 = -1.f, b1 = -1.f, b2 = -1.f;
        for (int i = 0; i < F; i++) {
            float v = a[i];
            if (v > b0)      { b2 = b1; c2 = c1; b1 = b0; c1 = c0; b0 = v; c0 = i; }
            else if (v > b1) { b2 = b1; c2 = c1; b1 = v; c1 = i; }
            else if (v > b2) { b2 = v; c2 = i; }
        }
        int fr[3] = {max(1, c0), max(1, c1), max(1, c2)};
        float av[3] = {a[fr[0]], a[fr[1]], a[fr[2]]};
        float mx = fmaxf(av[0], fmaxf(av[1], av[2]));
        float e0 = expf(av[0] - mx), e1 = expf(av[1] - mx), e2 = expf(av[2] - mx);
        float inv = 1.f / (e0 + e1 + e2);
        freqs[m * 3 + 0] = fr[0]; freqs[m * 3 + 1] = fr[1]; freqs[m * 3 + 2] = fr[2];
        wk[m * 3 + 0] = e0 * inv; wk[m * 3 + 1] = e1 * inv; wk[m * 3 + 2] = e2 * inv;
    }
    float s0 = slog[0], s1 = slog[1], s2 = slog[2];
    float mx = fmaxf(s0, fmaxf(s1, s2));
    float e0 = expf(s0 - mx), e1 = expf(s1 - mx), e2 = expf(s2 - mx);
    float inv = 3.f / (e0 + e1 + e2);
    sw[0] = e0 * inv; sw[1] = e1 * inv; sw[2] = e2 * inv;
}

// ---------------- prep: W2T[c][o] = sum_h w_ch[o,h]*pw_w[h,c] (bf16); Pb, S_ch ----------------
__global__ __launch_bounds__(256) void prep_w2(const float* __restrict__ w_ch,
        const float* __restrict__ pw_w, const float* __restrict__ pw_b,
        unsigned short* __restrict__ w2tb, float* __restrict__ pbs) {
    int tid = threadIdx.x;
    if (blockIdx.x == 64) {
        if (tid < 128) {
            float pb = 0.f, s = 0.f;
            for (int h = 0; h < HID; h++) {
                float w = w_ch[tid * HID + h];
                pb += w * pw_b[h]; s += w;
            }
            pbs[tid] = pb; pbs[128 + tid] = s;
        }
        return;
    }
    int idx = blockIdx.x * 256 + tid;
    int c = idx >> 7, o = idx & 127;
    float acc = 0.f;
    for (int h = 0; h < HID; h++) acc += w_ch[o * HID + h] * pw_w[h * CIN + c];
    w2tb[c * 128 + o] = f2bf(acc);
}

// ---------------- prep: w_t -> bf16 + row sums; one wave per row ----------------
__global__ __launch_bounds__(256) void prep_wt(const float* __restrict__ wt0,
        const float* __restrict__ wt1, const float* __restrict__ wt2,
        unsigned short* __restrict__ wtb, float* __restrict__ wsum) {
    int wid = blockIdx.x * 4 + (threadIdx.x >> 6);
    int lane = threadIdx.x & 63;
    const float* src; int T, p, m; size_t off;
    if (wid < 192)      { m = 0; p = wid;       src = wt0; T = 1024; off = 0; }
    else if (wid < 384) { m = 1; p = wid - 192; src = wt1; T = 512;  off = (size_t)192 * 1024; }
    else                { m = 2; p = wid - 384; src = wt2; T = 256;  off = (size_t)192 * 1024 + (size_t)192 * 512; }
    const float* row = src + (size_t)p * T;
    unsigned short* dst = wtb + off + (size_t)p * T;
    float s = 0.f;
    for (int j = lane; j < T; j += 64) { float v = row[j]; s += v; dst[j] = f2bf(v); }
#pragma unroll
    for (int d = 1; d < 64; d <<= 1) s += __shfl_xor(s, d);
    if (lane == 0) wsum[m * 192 + p] = s;
}

// ---------------- depthwise mix: dwmix[b,c,l] = dw_b[c] + sum_k wk_k*conv_k (bf16) ----------------
template<int T>
__global__ __launch_bounds__(256) void dwmix_k(const float* __restrict__ xm,
        const float* __restrict__ dw_w, const float* __restrict__ dw_b,
        const int* __restrict__ freqs, const float* __restrict__ wkbuf, int m,
        unsigned short* __restrict__ dwmix) {
    __shared__ __align__(16) unsigned short tile[CIN * 64];
    int tid = threadIdx.x;
    int b = blockIdx.y;
    int tile0 = blockIdx.x * 64;
    int j = tid & 63, cg = tid >> 6;                // 4 groups x 32 channels
    int l = tile0 + j;

    int   posv[27];
    float okw[27];
#pragma unroll
    for (int k = 0; k < 3; k++) {
        int   f   = freqs[m * 3 + k];
        float wkv = wkbuf[m * 3 + k];
        int p    = T / f;
        int rows = (T + p - 1) / p;
        int r  = l / p;
        int cc = l - r * p;
        int q = k * 9;
#pragma unroll
        for (int dr = -1; dr <= 1; dr++) {
#pragma unroll
            for (int dc = -1; dc <= 1; dc++) {
                int rr2 = r + dr, c2 = cc + dc;
                int pos = rr2 * p + c2;
                bool ok = (rr2 >= 0) && (rr2 < rows) && (c2 >= 0) && (c2 < p) && (pos < T);
                posv[q] = ok ? pos : 0;
                okw[q]  = ok ? wkv : 0.f;
                q++;
            }
        }
    }
#pragma unroll
    for (int i = 0; i < 32; i++) {
        int c = cg * 32 + i;
        const float* xr = xm + ((size_t)b * CIN + c) * T;
        const float* w9 = dw_w + c * 9;
        float s = dw_b[c];
#pragma unroll
        for (int q = 0; q < 9; q++) {
            float tmp = okw[q]      * xr[posv[q]]
                      + okw[9 + q]  * xr[posv[9 + q]]
                      + okw[18 + q] * xr[posv[18 + q]];
            s += w9[q] * tmp;
        }
        tile[c * 64 + j] = f2bf(s);
    }
    __syncthreads();
    const uint4* src = (const uint4*)tile;
#pragma unroll
    for (int i = 0; i < 4; i++) {
        int e = i * 256 + tid;                      // 1024 uint4 = 8192 bf16
        int c = e >> 3, seg = e & 7;
        *(uint4*)(dwmix + ((size_t)b * CIN + c) * T + tile0 + seg * 8) = src[e];
    }
}

// ---------------- tp GEMM: C[192][8192] = A[192][T] * B[8192][T]^T (bf16 MFMA) ----------------
template<int T>
__global__ __launch_bounds__(256) void tp_gemm(const unsigned short* __restrict__ A,
        const unsigned short* __restrict__ B, unsigned short* __restrict__ C) {
    __shared__ __align__(16) unsigned short As[64 * 72];   // stride 72 elem = 144 B (16-aligned, conflict-light)
    __shared__ __align__(16) unsigned short Bs[64 * 72];
    int tid = threadIdx.x;
    int lane = tid & 63, wave = tid >> 6;
    int wm = (wave >> 1) * 32, wn = (wave & 1) * 32;
    int p0 = blockIdx.x * 64, n0 = blockIdx.y * 64;
    f32x4 acc[2][2];
#pragma unroll
    for (int i = 0; i < 2; i++)
#pragma unroll
        for (int j = 0; j < 2; j++) acc[i][j] = (f32x4){0.f, 0.f, 0.f, 0.f};

    int r = tid >> 2, seg = tid & 3;
    const unsigned short* ga = A + (size_t)(p0 + r) * T + seg * 16;
    const unsigned short* gb = B + (size_t)(n0 + r) * T + seg * 16;
    unsigned short* la = &As[r * 72 + seg * 16];
    unsigned short* lb = &Bs[r * 72 + seg * 16];
    int fr = lane & 15, fk = (lane >> 4) * 8;

    for (int k0 = 0; k0 < T; k0 += 64) {
        __syncthreads();
        *(uint4*)la       = *(const uint4*)ga;
        *(uint4*)(la + 8) = *(const uint4*)(ga + 8);
        *(uint4*)lb       = *(const uint4*)gb;
        *(uint4*)(lb + 8) = *(const uint4*)(gb + 8);
        ga += 64; gb += 64;
        __syncthreads();
#pragma unroll
        for (int ks = 0; ks < 2; ks++) {
            int ko = ks * 32 + fk;
            s16x8 a0 = *(const s16x8*)&As[(wm + fr) * 72 + ko];
            s16x8 a1 = *(const s16x8*)&As[(wm + 16 + fr) * 72 + ko];
            s16x8 b0 = *(const s16x8*)&Bs[(wn + fr) * 72 + ko];
            s16x8 b1 = *(const s16x8*)&Bs[(wn + 16 + fr) * 72 + ko];
            acc[0][0] = __builtin_amdgcn_mfma_f32_16x16x32_bf16(a0, b0, acc[0][0], 0, 0, 0);
            acc[0][1] = __builtin_amdgcn_mfma_f32_16x16x32_bf16(a0, b1, acc[0][1], 0, 0, 0);
            acc[1][0] = __builtin_amdgcn_mfma_f32_16x16x32_bf16(a1, b0, acc[1][0], 0, 0, 0);
            acc[1][1] = __builtin_amdgcn_mfma_f32_16x16x32_bf16(a1, b1, acc[1][1], 0, 0, 0);
        }
    }
    int crow = (lane >> 4) * 4, ccol = lane & 15;
#pragma unroll
    for (int i = 0; i < 2; i++)
#pragma unroll
        for (int j = 0; j < 2; j++) {
            int col = n0 + wn + j * 16 + ccol;
#pragma unroll
            for (int reg = 0; reg < 4; reg++) {
                int row = p0 + wm + i * 16 + crow + reg;
                C[(size_t)row * 8192 + col] = f2bf(acc[i][j][reg]);
            }
        }
}

// ---------------- final: out = residual + sum_m sw_m*(W2@tp_m + biases) ----------------
__global__ __launch_bounds__(256) void final_out(const float* __restrict__ x,
        const unsigned short* __restrict__ tp, const unsigned short* __restrict__ w2tb,
        const float* __restrict__ pbs, const float* __restrict__ wsum,
        const float* __restrict__ bt0, const float* __restrict__ bt1,
        const float* __restrict__ bt2, const float* __restrict__ b_ch,
        const float* __restrict__ swb, float* __restrict__ out) {
    __shared__ unsigned short w2s[128 * 128];       // [c][o] bf16, 32 KB
    __shared__ float tps[2][128];
    int tid = threadIdx.x;
#pragma unroll
    for (int i = 0; i < 64; i++) w2s[i * 256 + tid] = w2tb[i * 256 + tid];
    float sw0 = swb[0], sw1 = swb[1], sw2 = swb[2];
    int o = tid & 127, rw = tid >> 7;
    float pbv  = pbs[o];
    float schv = pbs[128 + o];
    float bchv = (sw0 + sw1 + sw2) * b_ch[o];

    for (int pr = 0; pr < 16; pr++) {
        __syncthreads();
        {
            int rr = tid >> 7, c = tid & 127;
            int r2 = blockIdx.x * 32 + pr * 2 + rr;
            int b2 = r2 / 192, p2 = r2 - b2 * 192;
            size_t base = (size_t)p2 * 8192 + (size_t)b2 * 128 + c;
            tps[rr][c] = sw0 * bf2f(tp[base])
                       + sw1 * bf2f(tp[1572864 + base])
                       + sw2 * bf2f(tp[3145728 + base]);
        }
        __syncthreads();
        int r = blockIdx.x * 32 + pr * 2 + rw;
        int b = r / 192, p = r - b * 192;
        float acc = 0.f;
#pragma unroll 8
        for (int c = 0; c < 128; c++) acc += bf2f(w2s[c * 128 + o]) * tps[rw][c];
        float wsv = sw0 * wsum[p] + sw1 * wsum[192 + p] + sw2 * wsum[384 + p];
        float btv = sw0 * bt0[p] + sw1 * bt1[p] + sw2 * bt2[p];
        float res = x[((size_t)b * T0 + (T0 - PRED) + p) * CIN + o];
        out[(size_t)r * TGT + o] = res + acc + pbv * wsv + schv * btv + bchv;
    }
}

extern "C" void kernel_launch(void* const* d_in, const int* in_sizes, int n_in,
                              void* d_out, int out_size, void* d_ws, size_t ws_size,
                              hipStream_t stream) {
    const float* x    = (const float*)d_in[0];
    const float* dw_w = (const float*)d_in[1];
    const float* dw_b = (const float*)d_in[2];
    const float* pw_w = (const float*)d_in[3];
    const float* pw_b = (const float*)d_in[4];
    const float* wt0  = (const float*)d_in[5];
    const float* bt0  = (const float*)d_in[6];
    const float* wt1  = (const float*)d_in[7];
    const float* bt1  = (const float*)d_in[8];
    const float* wt2  = (const float*)d_in[9];
    const float* bt2  = (const float*)d_in[10];
    const float* w_ch = (const float*)d_in[11];
    const float* b_ch = (const float*)d_in[12];
    const float* slog = (const float*)d_in[13];
    float* out = (float*)d_out;
    float* ws  = (float*)d_ws;

    float* xct   = ws + XCT_OFF;
    float* s1b   = ws + S1_OFF;
    float* s2b   = ws + S2_OFF;
    float* parts = ws + P0_OFF;
    float* ampsb = ws + AMPS_OFF;
    int*   freqs = (int*)(ws + META_OFF);
    float* wkb   = ws + META_OFF + 16;
    float* swb   = ws + META_OFF + 32;
    unsigned short* w2tb  = (unsigned short*)(ws + W2T_OFF);
    float* pbs   = ws + PBS_OFF;
    float* wsumb = ws + WSUM_OFF;
    unsigned short* wtb   = (unsigned short*)(ws + WTB_OFF);
    unsigned short* dwm   = (unsigned short*)(ws + DWMIX_OFF);
    unsigned short* tpb   = (unsigned short*)(ws + TP_OFF);

    const size_t WT1O = (size_t)192 * 1024;
    const size_t WT2O = WT1O + (size_t)192 * 512;
    const size_t TPPL = (size_t)192 * 8192;

    transpose_x<<<dim3(32, 4, NB), dim3(32, 8, 1), 0, stream>>>(x, xct);
    pool2<9><<<2048, 256, 0, stream>>>(xct, s1b, NROWS * 512);
    pool2<8><<<1024, 256, 0, stream>>>(s1b, s2b, NROWS * 256);

    fft_amps<10><<<1024, 256, 0, stream>>>(xct, parts, 520);
    fft_amps<9><<<1024, 256, 0, stream>>>(s1b, parts + (size_t)1024 * 520, 264);
    fft_amps<8><<<1024, 256, 0, stream>>>(s2b, parts + (size_t)1024 * 520 + (size_t)1024 * 264, 136);
    reduce_amps<<<dim3(9, 3), 256, 0, stream>>>(parts, ampsb);
    meta_topk<<<1, 64, 0, stream>>>(ampsb, slog, freqs, wkb, swb);

    prep_w2<<<65, 256, 0, stream>>>(w_ch, pw_w, pw_b, w2tb, pbs);
    prep_wt<<<144, 256, 0, stream>>>(wt0, wt1, wt2, wtb, wsumb);

    // scale 0 (T=1024)
    dwmix_k<1024><<<dim3(16, NB), 256, 0, stream>>>(xct, dw_w, dw_b, freqs, wkb, 0, dwm);
    tp_gemm<1024><<<dim3(3, 128), 256, 0, stream>>>(wtb, dwm, tpb);
    // scale 1 (T=512)
    dwmix_k<512><<<dim3(8, NB), 256, 0, stream>>>(s1b, dw_w, dw_b, freqs, wkb, 1, dwm);
    tp_gemm<512><<<dim3(3, 128), 256, 0, stream>>>(wtb + WT1O, dwm, tpb + TPPL);
    // scale 2 (T=256)
    dwmix_k<256><<<dim3(4, NB), 256, 0, stream>>>(s2b, dw_w, dw_b, freqs, wkb, 2, dwm);
    tp_gemm<256><<<dim3(3, 128), 256, 0, stream>>>(wtb + WT2O, dwm, tpb + 2 * TPPL);

    final_out<<<384, 256, 0, stream>>>(x, tpb, w2tb, pbs, wsumb,
                                       bt0, bt1, bt2, b_ch, swb, out);
}

// Round 3
// 403.908 us; speedup vs baseline: 2.4645x; 1.4306x over previous
//
#include <hip/hip_runtime.h>
#include <math.h>

#define NB   64
#define T0   1024
#define CIN  128
#define HID  256
#define TGT  128
#define PRED 192
#define NROWS (NB*CIN)

typedef __attribute__((ext_vector_type(4))) float f32x4;
typedef __attribute__((ext_vector_type(8))) short s16x8;

// ---------------- workspace layout (float offsets) ----------------
static const size_t XCT_OFF   = 0;          // [64][128][1024] f32
static const size_t S1_OFF    = 8388608;    // [64][128][512]
static const size_t S2_OFF    = 12582912;   // [64][128][256]
static const size_t P0_OFF    = 14680064;   // [1024][520]
static const size_t P1_OFF    = 15212544;   // [1024][264]
static const size_t P2_OFF    = 15482880;   // [1024][136]
static const size_t AMPS_OFF  = 15622144;   // 1024
static const size_t META_OFF  = 15623168;   // 64: freqs int[9]@0, wk f32[9]@16, sw f32[3]@32
static const size_t W2T_OFF   = 15623232;   // [128 c][128 o] bf16
static const size_t PBS_OFF   = 15639616;   // Pb[128], S_ch[128] f32
static const size_t WSUM_OFF  = 15639872;   // [3][192] f32
static const size_t WTB_OFF   = 15640448;   // bf16 w_t
static const size_t DWMIX_OFF = 15812480;   // bf16 [8192][T]
static const size_t TP_OFF    = 20006784;   // bf16 [3][192][8192]
// end = 22366080 floats = 89.5 MB

__device__ inline unsigned short f2bf(float x) {
    union { float f; unsigned u; } v; v.f = x;
    unsigned r = (v.u + 0x7FFFu + ((v.u >> 16) & 1u)) >> 16;
    return (unsigned short)r;
}
__device__ inline float bf2f(unsigned short u) {
    union { unsigned u; float f; } v; v.u = ((unsigned)u) << 16;
    return v.f;
}

// ---------------- transpose x[B,T,C] -> xct[B,C,T] ----------------
__global__ __launch_bounds__(256) void transpose_x(const float* __restrict__ x,
                                                   float* __restrict__ xct) {
    __shared__ float tile[32][33];
    int b = blockIdx.z;
    int t0 = blockIdx.x * 32, c0 = blockIdx.y * 32;
    int tx = threadIdx.x, ty = threadIdx.y;
#pragma unroll
    for (int i = 0; i < 4; i++) {
        int t = t0 + ty + i * 8, c = c0 + tx;
        tile[ty + i * 8][tx] = x[((size_t)b * T0 + t) * CIN + c];
    }
    __syncthreads();
#pragma unroll
    for (int i = 0; i < 4; i++) {
        int c = c0 + ty + i * 8, t = t0 + tx;
        xct[((size_t)b * CIN + c) * T0 + t] = tile[tx][ty + i * 8];
    }
}

// ---------------- stride-2 average pool ----------------
template<int LOGOUT>
__global__ __launch_bounds__(256) void pool2(const float* __restrict__ in,
                                             float* __restrict__ out, int n_out) {
    const int tmask = (1 << LOGOUT) - 1;
    for (int idx = blockIdx.x * 256 + threadIdx.x; idx < n_out; idx += gridDim.x * 256) {
        int row = idx >> LOGOUT;
        int jj  = idx & tmask;
        const float* r = in + (((size_t)row) << (LOGOUT + 1));
        out[idx] = 0.5f * (r[2 * jj] + r[2 * jj + 1]);
    }
}

// ---------------- FFT: 2 real rows packed per complex FFT, 8 rows/block ----------------
template<int LOGT>
__global__ __launch_bounds__(256) void fft_amps(const float* __restrict__ xm,
                                                float* __restrict__ part, int pad) {
    constexpr int T = 1 << LOGT;
    constexpr int F = T / 2;
    __shared__ float re[T], im[T];
    __shared__ float twc[F], tws[F];
    __shared__ float acc[F + 1];
    int tid = threadIdx.x;
    for (int j = tid; j < F; j += 256) {
        float s, c;
        sincosf(-6.283185307179586f * (float)j / (float)T, &s, &c);
        twc[j] = c; tws[j] = s;
    }
    for (int i = tid; i <= F; i += 256) acc[i] = 0.f;
    __syncthreads();

    int rowbase = blockIdx.x * 8;
    for (int pr = 0; pr < 4; pr++) {
        const float* row0 = xm + (size_t)(rowbase + 2 * pr) * T;
        const float* row1 = row0 + T;
        for (int j = tid; j < T; j += 256) {
            int rv = (int)(__brev((unsigned)j) >> (32 - LOGT));
            re[rv] = row0[j];
            im[rv] = row1[j];
        }
        __syncthreads();
        for (int s = 1; s <= LOGT; s++) {
            int mh = 1 << (s - 1);
            for (int bf = tid; bf < T / 2; bf += 256) {
                int k  = bf & (mh - 1);
                int g  = bf >> (s - 1);
                int i1 = (g << s) + k;
                int i2 = i1 + mh;
                int twi = k << (LOGT - s);
                float wr = twc[twi], wi = tws[twi];
                float xr = re[i2], xi = im[i2];
                float tr = wr * xr - wi * xi;
                float ti = wr * xi + wi * xr;
                float ur = re[i1], ui = im[i1];
                re[i1] = ur + tr; im[i1] = ui + ti;
                re[i2] = ur - tr; im[i2] = ui - ti;
            }
            __syncthreads();
        }
        for (int f = tid; f <= F; f += 256) {
            if (f >= 1) {
                int mf = T - f;
                float rf = re[f], imf = im[f];
                float rm = re[mf], imm = im[mf];
                float m0 = sqrtf((rf + rm) * (rf + rm) + (imf - imm) * (imf - imm));
                float m1 = sqrtf((imf + imm) * (imf + imm) + (rf - rm) * (rf - rm));
                acc[f] += 0.5f * (m0 + m1);
            }
        }
        __syncthreads();
    }
    for (int f = tid; f <= F; f += 256)
        part[(size_t)blockIdx.x * pad + f] = acc[f];
}

// ---------------- deterministic reduce of partials -> amps (mean) ----------------
__global__ __launch_bounds__(256) void reduce_amps(const float* __restrict__ parts,
                                                   float* __restrict__ amps) {
    const int PADs[3] = {520, 264, 136};
    const int Fs[3]   = {513, 257, 129};
    const size_t POFF[3] = {0, (size_t)1024 * 520, (size_t)1024 * 520 + (size_t)1024 * 264};
    const int AOFF[3] = {0, 520, 780};
    int s  = blockIdx.y;
    int fl = threadIdx.x & 63;
    int rg = threadIdx.x >> 6;
    int f  = blockIdx.x * 64 + fl;
    bool valid = f < Fs[s];
    const float* base = parts + POFF[s];
    int pad = PADs[s];
    float sum = 0.f;
    if (valid)
        for (int r = rg; r < 1024; r += 4) sum += base[(size_t)r * pad + f];
    __shared__ float red[256];
    red[threadIdx.x] = sum;
    __syncthreads();
    if (rg == 0 && valid) {
        float tot = red[fl] + red[fl + 64] + red[fl + 128] + red[fl + 192];
        amps[AOFF[s] + f] = tot * (1.f / 8192.f);
    }
}

// ---------------- top-3: parallel, deterministic (value desc, index asc ties) ----------------
__device__ inline void ins3(float v, int i, float& b0, int& c0,
                            float& b1, int& c1, float& b2, int& c2) {
    bool g0 = (v > b0) || (v == b0 && i < c0);
    bool g1 = (v > b1) || (v == b1 && i < c1);
    bool g2 = (v > b2) || (v == b2 && i < c2);
    if (g0)      { b2 = b1; c2 = c1; b1 = b0; c1 = c0; b0 = v; c0 = i; }
    else if (g1) { b2 = b1; c2 = c1; b1 = v; c1 = i; }
    else if (g2) { b2 = v; c2 = i; }
}

__global__ __launch_bounds__(256) void meta_topk(const float* __restrict__ amps,
                          const float* __restrict__ slog,
                          int* __restrict__ freqs, float* __restrict__ wk,
                          float* __restrict__ sw) {
    __shared__ float sv[12];
    __shared__ int   si[12];
    const int offs[3] = {0, 520, 780};
    const int Fs[3]   = {513, 257, 129};
    int tid = threadIdx.x, lane = tid & 63, wv = tid >> 6;
    for (int m = 0; m < 3; m++) {
        const float* a = amps + offs[m];
        int F = Fs[m];
        float b0 = -1e30f, b1 = -1e30f, b2 = -1e30f;
        int   c0 = 0x7fffffff, c1 = 0x7fffffff, c2 = 0x7fffffff;
        for (int i = tid; i < F; i += 256)
            ins3(a[i], i, b0, c0, b1, c1, b2, c2);
#pragma unroll
        for (int d = 1; d < 64; d <<= 1) {
            float o0 = __shfl_xor(b0, d), o1 = __shfl_xor(b1, d), o2 = __shfl_xor(b2, d);
            int   i0 = __shfl_xor(c0, d), i1 = __shfl_xor(c1, d), i2 = __shfl_xor(c2, d);
            ins3(o0, i0, b0, c0, b1, c1, b2, c2);
            ins3(o1, i1, b0, c0, b1, c1, b2, c2);
            ins3(o2, i2, b0, c0, b1, c1, b2, c2);
        }
        if (lane == 0) {
            sv[wv * 3 + 0] = b0; si[wv * 3 + 0] = c0;
            sv[wv * 3 + 1] = b1; si[wv * 3 + 1] = c1;
            sv[wv * 3 + 2] = b2; si[wv * 3 + 2] = c2;
        }
        __syncthreads();
        if (tid == 0) {
            float d0 = sv[0], d1 = sv[1], d2 = sv[2];
            int   e0 = si[0], e1 = si[1], e2 = si[2];
            for (int q = 3; q < 12; q++) ins3(sv[q], si[q], d0, e0, d1, e1, d2, e2);
            int fr[3] = {max(1, e0), max(1, e1), max(1, e2)};
            float av[3] = {a[fr[0]], a[fr[1]], a[fr[2]]};
            float mx = fmaxf(av[0], fmaxf(av[1], av[2]));
            float x0 = expf(av[0] - mx), x1 = expf(av[1] - mx), x2 = expf(av[2] - mx);
            float inv = 1.f / (x0 + x1 + x2);
            freqs[m * 3 + 0] = fr[0]; freqs[m * 3 + 1] = fr[1]; freqs[m * 3 + 2] = fr[2];
            wk[m * 3 + 0] = x0 * inv; wk[m * 3 + 1] = x1 * inv; wk[m * 3 + 2] = x2 * inv;
        }
        __syncthreads();
    }
    if (tid == 0) {
        float s0 = slog[0], s1 = slog[1], s2 = slog[2];
        float mx = fmaxf(s0, fmaxf(s1, s2));
        float e0 = expf(s0 - mx), e1 = expf(s1 - mx), e2 = expf(s2 - mx);
        float inv = 3.f / (e0 + e1 + e2);
        sw[0] = e0 * inv; sw[1] = e1 * inv; sw[2] = e2 * inv;
    }
}

// ---------------- prep: W2T[c][o] = sum_h w_ch[o,h]*pw_w[h,c] (bf16); Pb, S_ch ----------------
__global__ __launch_bounds__(256) void prep_w2(const float* __restrict__ w_ch,
        const float* __restrict__ pw_w, const float* __restrict__ pw_b,
        unsigned short* __restrict__ w2tb, float* __restrict__ pbs) {
    int tid = threadIdx.x;
    if (blockIdx.x == 64) {
        if (tid < 128) {
            float pb = 0.f, s = 0.f;
            for (int h = 0; h < HID; h++) {
                float w = w_ch[tid * HID + h];
                pb += w * pw_b[h]; s += w;
            }
            pbs[tid] = pb; pbs[128 + tid] = s;
        }
        return;
    }
    int idx = blockIdx.x * 256 + tid;
    int c = idx >> 7, o = idx & 127;
    float acc = 0.f;
    for (int h = 0; h < HID; h++) acc += w_ch[o * HID + h] * pw_w[h * CIN + c];
    w2tb[c * 128 + o] = f2bf(acc);
}

// ---------------- prep: w_t -> bf16 + row sums ----------------
__global__ __launch_bounds__(256) void prep_wt(const float* __restrict__ wt0,
        const float* __restrict__ wt1, const float* __restrict__ wt2,
        unsigned short* __restrict__ wtb, float* __restrict__ wsum) {
    int wid = blockIdx.x * 4 + (threadIdx.x >> 6);
    int lane = threadIdx.x & 63;
    const float* src; int T, p, m; size_t off;
    if (wid < 192)      { m = 0; p = wid;       src = wt0; T = 1024; off = 0; }
    else if (wid < 384) { m = 1; p = wid - 192; src = wt1; T = 512;  off = (size_t)192 * 1024; }
    else                { m = 2; p = wid - 384; src = wt2; T = 256;  off = (size_t)192 * 1024 + (size_t)192 * 512; }
    const float* row = src + (size_t)p * T;
    unsigned short* dst = wtb + off + (size_t)p * T;
    float s = 0.f;
    for (int j = lane; j < T; j += 64) { float v = row[j]; s += v; dst[j] = f2bf(v); }
#pragma unroll
    for (int d = 1; d < 64; d <<= 1) s += __shfl_xor(s, d);
    if (lane == 0) wsum[m * 192 + p] = s;
}

// ---------------- depthwise mix, LDS-staged rows + 9-bit tap masks ----------------
// dwmix[b,c,l] = dw_b[c] + sum_k wk_k * sum_q w9[c,q] * x[l + dr*p_k + dc] (masked)
template<int T, int CPB>
__global__ __launch_bounds__(256) void dwmix_k(const float* __restrict__ xm,
        const float* __restrict__ dw_w, const float* __restrict__ dw_b,
        const int* __restrict__ freqs, const float* __restrict__ wkbuf, int m,
        unsigned short* __restrict__ dwmix) {
    constexpr int RS = T + 8;                  // padded row stride (bank-spreads channels)
    constexpr int JS = 256 / CPB;              // threads per channel
    __shared__ float xs[CPB * RS];
    __shared__ unsigned short msk[3 * T];
    int tid = threadIdx.x;
    int b = blockIdx.y;
    int c0 = blockIdx.x * CPB;

    int pk[3]; float wkv[3];
#pragma unroll
    for (int k = 0; k < 3; k++) {
        int f = freqs[m * 3 + k];
        pk[k] = T / f;
        wkv[k] = wkbuf[m * 3 + k];
    }
    // stage CPB rows (coalesced float4) + zero slot at row offset T
    const float* src = xm + ((size_t)b * CIN + c0) * T;
    for (int i = tid; i < CPB * (T / 4); i += 256) {
        int ch = i / (T / 4), seg = i - ch * (T / 4);
        *(float4*)&xs[ch * RS + seg * 4] = *(const float4*)&src[(size_t)ch * T + seg * 4];
    }
    if (tid < CPB) xs[tid * RS + T] = 0.f;
    // build 9-bit validity masks per (k, l)
    for (int l = tid; l < T; l += 256) {
#pragma unroll
        for (int k = 0; k < 3; k++) {
            int p = pk[k];
            int rows = (T + p - 1) / p;
            int r = l / p, cc = l - r * p;
            unsigned mm = 0; int q = 0;
#pragma unroll
            for (int dr = -1; dr <= 1; dr++)
#pragma unroll
                for (int dc = -1; dc <= 1; dc++, q++) {
                    int rr2 = r + dr, c2 = cc + dc;
                    int pos = l + dr * p + dc;
                    if (rr2 >= 0 && rr2 < rows && c2 >= 0 && c2 < p && pos < T)
                        mm |= 1u << q;
                }
            msk[k * T + l] = (unsigned short)mm;
        }
    }
    __syncthreads();

    int ch = tid / JS, j = tid - ch * JS;
    int c = c0 + ch;
    float w9[9];
#pragma unroll
    for (int q = 0; q < 9; q++) w9[q] = dw_w[c * 9 + q];
    float bias = dw_b[c];
    int cb = ch * RS;
    unsigned short* outp = dwmix + ((size_t)b * CIN + c) * T;

    for (int i = 0; i < 32; i++) {
        int l = j + i * JS;
        float s = bias;
#pragma unroll
        for (int k = 0; k < 3; k++) {
            int p = pk[k];
            unsigned mm = msk[k * T + l];
            float sk = 0.f;
            int q = 0;
#pragma unroll
            for (int dr = -1; dr <= 1; dr++) {
                int rowoff = l + dr * p;
#pragma unroll
                for (int dc = -1; dc <= 1; dc++, q++) {
                    int pos = rowoff + dc;
                    int addr = ((mm >> q) & 1) ? pos : T;   // masked -> zero slot
                    sk += w9[q] * xs[cb + addr];
                }
            }
            s += wkv[k] * sk;
        }
        outp[l] = f2bf(s);
    }
}

// ---------------- tp GEMM: C[192][8192] = A[192][T] * B[8192][T]^T (bf16 MFMA) ----------------
template<int T>
__global__ __launch_bounds__(256) void tp_gemm(const unsigned short* __restrict__ A,
        const unsigned short* __restrict__ B, unsigned short* __restrict__ C) {
    __shared__ __align__(16) unsigned short As[64 * 72];
    __shared__ __align__(16) unsigned short Bs[64 * 72];
    int tid = threadIdx.x;
    int lane = tid & 63, wave = tid >> 6;
    int wm = (wave >> 1) * 32, wn = (wave & 1) * 32;
    int p0 = blockIdx.x * 64, n0 = blockIdx.y * 64;
    f32x4 acc[2][2];
#pragma unroll
    for (int i = 0; i < 2; i++)
#pragma unroll
        for (int j = 0; j < 2; j++) acc[i][j] = (f32x4){0.f, 0.f, 0.f, 0.f};

    int r = tid >> 2, seg = tid & 3;
    const unsigned short* ga = A + (size_t)(p0 + r) * T + seg * 16;
    const unsigned short* gb = B + (size_t)(n0 + r) * T + seg * 16;
    unsigned short* la = &As[r * 72 + seg * 16];
    unsigned short* lb = &Bs[r * 72 + seg * 16];
    int fr = lane & 15, fk = (lane >> 4) * 8;

    for (int k0 = 0; k0 < T; k0 += 64) {
        __syncthreads();
        *(uint4*)la       = *(const uint4*)ga;
        *(uint4*)(la + 8) = *(const uint4*)(ga + 8);
        *(uint4*)lb       = *(const uint4*)gb;
        *(uint4*)(lb + 8) = *(const uint4*)(gb + 8);
        ga += 64; gb += 64;
        __syncthreads();
#pragma unroll
        for (int ks = 0; ks < 2; ks++) {
            int ko = ks * 32 + fk;
            s16x8 a0 = *(const s16x8*)&As[(wm + fr) * 72 + ko];
            s16x8 a1 = *(const s16x8*)&As[(wm + 16 + fr) * 72 + ko];
            s16x8 b0 = *(const s16x8*)&Bs[(wn + fr) * 72 + ko];
            s16x8 b1 = *(const s16x8*)&Bs[(wn + 16 + fr) * 72 + ko];
            acc[0][0] = __builtin_amdgcn_mfma_f32_16x16x32_bf16(a0, b0, acc[0][0], 0, 0, 0);
            acc[0][1] = __builtin_amdgcn_mfma_f32_16x16x32_bf16(a0, b1, acc[0][1], 0, 0, 0);
            acc[1][0] = __builtin_amdgcn_mfma_f32_16x16x32_bf16(a1, b0, acc[1][0], 0, 0, 0);
            acc[1][1] = __builtin_amdgcn_mfma_f32_16x16x32_bf16(a1, b1, acc[1][1], 0, 0, 0);
        }
    }
    int crow = (lane >> 4) * 4, ccol = lane & 15;
#pragma unroll
    for (int i = 0; i < 2; i++)
#pragma unroll
        for (int j = 0; j < 2; j++) {
            int col = n0 + wn + j * 16 + ccol;
#pragma unroll
            for (int reg = 0; reg < 4; reg++) {
                int row = p0 + wm + i * 16 + crow + reg;
                C[(size_t)row * 8192 + col] = f2bf(acc[i][j][reg]);
            }
        }
}

// ---------------- final: out = residual + sum_m sw_m*(W2@tp_m + biases) ----------------
__global__ __launch_bounds__(256) void final_out(const float* __restrict__ x,
        const unsigned short* __restrict__ tp, const unsigned short* __restrict__ w2tb,
        const float* __restrict__ pbs, const float* __restrict__ wsum,
        const float* __restrict__ bt0, const float* __restrict__ bt1,
        const float* __restrict__ bt2, const float* __restrict__ b_ch,
        const float* __restrict__ swb, float* __restrict__ out) {
    __shared__ unsigned short w2s[128 * 128];
    __shared__ float tps[2][128];
    int tid = threadIdx.x;
#pragma unroll
    for (int i = 0; i < 64; i++) w2s[i * 256 + tid] = w2tb[i * 256 + tid];
    float sw0 = swb[0], sw1 = swb[1], sw2 = swb[2];
    int o = tid & 127, rw = tid >> 7;
    float pbv  = pbs[o];
    float schv = pbs[128 + o];
    float bchv = (sw0 + sw1 + sw2) * b_ch[o];

    for (int pr = 0; pr < 16; pr++) {
        __syncthreads();
        {
            int rr = tid >> 7, c = tid & 127;
            int r2 = blockIdx.x * 32 + pr * 2 + rr;
            int b2 = r2 / 192, p2 = r2 - b2 * 192;
            size_t base = (size_t)p2 * 8192 + (size_t)b2 * 128 + c;
            tps[rr][c] = sw0 * bf2f(tp[base])
                       + sw1 * bf2f(tp[1572864 + base])
                       + sw2 * bf2f(tp[3145728 + base]);
        }
        __syncthreads();
        int r = blockIdx.x * 32 + pr * 2 + rw;
        int b = r / 192, p = r - b * 192;
        float acc = 0.f;
#pragma unroll 8
        for (int c = 0; c < 128; c++) acc += bf2f(w2s[c * 128 + o]) * tps[rw][c];
        float wsv = sw0 * wsum[p] + sw1 * wsum[192 + p] + sw2 * wsum[384 + p];
        float btv = sw0 * bt0[p] + sw1 * bt1[p] + sw2 * bt2[p];
        float res = x[((size_t)b * T0 + (T0 - PRED) + p) * CIN + o];
        out[(size_t)r * TGT + o] = res + acc + pbv * wsv + schv * btv + bchv;
    }
}

extern "C" void kernel_launch(void* const* d_in, const int* in_sizes, int n_in,
                              void* d_out, int out_size, void* d_ws, size_t ws_size,
                              hipStream_t stream) {
    const float* x    = (const float*)d_in[0];
    const float* dw_w = (const float*)d_in[1];
    const float* dw_b = (const float*)d_in[2];
    const float* pw_w = (const float*)d_in[3];
    const float* pw_b = (const float*)d_in[4];
    const float* wt0  = (const float*)d_in[5];
    const float* bt0  = (const float*)d_in[6];
    const float* wt1  = (const float*)d_in[7];
    const float* bt1  = (const float*)d_in[8];
    const float* wt2  = (const float*)d_in[9];
    const float* bt2  = (const float*)d_in[10];
    const float* w_ch = (const float*)d_in[11];
    const float* b_ch = (const float*)d_in[12];
    const float* slog = (const float*)d_in[13];
    float* out = (float*)d_out;
    float* ws  = (float*)d_ws;

    float* xct   = ws + XCT_OFF;
    float* s1b   = ws + S1_OFF;
    float* s2b   = ws + S2_OFF;
    float* parts = ws + P0_OFF;
    float* ampsb = ws + AMPS_OFF;
    int*   freqs = (int*)(ws + META_OFF);
    float* wkb   = ws + META_OFF + 16;
    float* swb   = ws + META_OFF + 32;
    unsigned short* w2tb  = (unsigned short*)(ws + W2T_OFF);
    float* pbs   = ws + PBS_OFF;
    float* wsumb = ws + WSUM_OFF;
    unsigned short* wtb   = (unsigned short*)(ws + WTB_OFF);
    unsigned short* dwm   = (unsigned short*)(ws + DWMIX_OFF);
    unsigned short* tpb   = (unsigned short*)(ws + TP_OFF);

    const size_t WT1O = (size_t)192 * 1024;
    const size_t WT2O = WT1O + (size_t)192 * 512;
    const size_t TPPL = (size_t)192 * 8192;

    transpose_x<<<dim3(32, 4, NB), dim3(32, 8, 1), 0, stream>>>(x, xct);
    pool2<9><<<2048, 256, 0, stream>>>(xct, s1b, NROWS * 512);
    pool2<8><<<1024, 256, 0, stream>>>(s1b, s2b, NROWS * 256);

    fft_amps<10><<<1024, 256, 0, stream>>>(xct, parts, 520);
    fft_amps<9><<<1024, 256, 0, stream>>>(s1b, parts + (size_t)1024 * 520, 264);
    fft_amps<8><<<1024, 256, 0, stream>>>(s2b, parts + (size_t)1024 * 520 + (size_t)1024 * 264, 136);
    reduce_amps<<<dim3(9, 3), 256, 0, stream>>>(parts, ampsb);
    meta_topk<<<1, 256, 0, stream>>>(ampsb, slog, freqs, wkb, swb);

    prep_w2<<<65, 256, 0, stream>>>(w_ch, pw_w, pw_b, w2tb, pbs);
    prep_wt<<<144, 256, 0, stream>>>(wt0, wt1, wt2, wtb, wsumb);

    // scale 0 (T=1024)
    dwmix_k<1024, 8><<<dim3(16, NB), 256, 0, stream>>>(xct, dw_w, dw_b, freqs, wkb, 0, dwm);
    tp_gemm<1024><<<dim3(3, 128), 256, 0, stream>>>(wtb, dwm, tpb);
    // scale 1 (T=512)
    dwmix_k<512, 16><<<dim3(8, NB), 256, 0, stream>>>(s1b, dw_w, dw_b, freqs, wkb, 1, dwm);
    tp_gemm<512><<<dim3(3, 128), 256, 0, stream>>>(wtb + WT1O, dwm, tpb + TPPL);
    // scale 2 (T=256)
    dwmix_k<256, 32><<<dim3(4, NB), 256, 0, stream>>>(s2b, dw_w, dw_b, freqs, wkb, 2, dwm);
    tp_gemm<256><<<dim3(3, 128), 256, 0, stream>>>(wtb + WT2O, dwm, tpb + 2 * TPPL);

    final_out<<<384, 256, 0, stream>>>(x, tpb, w2tb, pbs, wsumb,
                                       bt0, bt1, bt2, b_ch, swb, out);
}

// Round 4
// 345.591 us; speedup vs baseline: 2.8804x; 1.1687x over previous
//
#include <hip/hip_runtime.h>
#include <math.h>

#define NB   64
#define T0   1024
#define CIN  128
#define HID  256
#define TGT  128
#define PRED 192
#define NROWS (NB*CIN)

typedef __attribute__((ext_vector_type(4))) float f32x4;
typedef __attribute__((ext_vector_type(8))) short s16x8;

// ---------------- workspace layout (float offsets) ----------------
static const size_t XCT_OFF   = 0;          // [64][128][1024] f32
static const size_t S1_OFF    = 8388608;    // [64][128][512]
static const size_t S2_OFF    = 12582912;   // [64][128][256]
static const size_t P0_OFF    = 14680064;   // [1024][520]
static const size_t P1_OFF    = 15212544;   // [1024][264]
static const size_t P2_OFF    = 15482880;   // [1024][136]
static const size_t AMPS_OFF  = 15622144;   // 1024
static const size_t META_OFF  = 15623168;   // 64: freqs int[9]@0, wk f32[9]@16, sw f32[3]@32
static const size_t W2T_OFF   = 15623232;   // [128 o][128 c-swizzled] bf16
static const size_t PBS_OFF   = 15639616;   // Pb[128], S_ch[128] f32
static const size_t WSUM_OFF  = 15639872;   // [3][192] f32
static const size_t WTB_OFF   = 15640448;   // bf16 w_t
static const size_t DWMIX_OFF = 15812480;   // bf16 [8192][T]
static const size_t TP_OFF    = 20006784;   // bf16 [3][192][8192]
// end = 22366080 floats = 89.5 MB

__device__ inline unsigned short f2bf(float x) {
    union { float f; unsigned u; } v; v.f = x;
    unsigned r = (v.u + 0x7FFFu + ((v.u >> 16) & 1u)) >> 16;
    return (unsigned short)r;
}
__device__ inline float bf2f(unsigned short u) {
    union { unsigned u; float f; } v; v.u = ((unsigned)u) << 16;
    return v.f;
}

// ---------------- fused: transpose x[B,T,C]->xct[B,C,T] + pool1 + pool2 ----------------
__global__ __launch_bounds__(256) void front(const float* __restrict__ x,
        float* __restrict__ xct, float* __restrict__ s1, float* __restrict__ s2) {
    __shared__ float tile[32][33];
    int b = blockIdx.z;
    int t0 = blockIdx.x * 32, c0 = blockIdx.y * 32;
    int tx = threadIdx.x, ty = threadIdx.y;       // 32 x 8
#pragma unroll
    for (int i = 0; i < 4; i++) {
        int t = t0 + ty + i * 8, c = c0 + tx;
        tile[ty + i * 8][tx] = x[((size_t)b * T0 + t) * CIN + c];
    }
    __syncthreads();
#pragma unroll
    for (int i = 0; i < 4; i++) {
        int c = c0 + ty + i * 8, cc = ty + i * 8;
        xct[((size_t)b * CIN + c) * T0 + t0 + tx] = tile[tx][cc];
        if (tx < 16) {
            float v = 0.5f * (tile[2 * tx][cc] + tile[2 * tx + 1][cc]);
            s1[((size_t)b * CIN + c) * (T0 / 2) + t0 / 2 + tx] = v;
        }
        if (tx < 8) {
            float v = 0.25f * (tile[4 * tx][cc] + tile[4 * tx + 1][cc]
                             + tile[4 * tx + 2][cc] + tile[4 * tx + 3][cc]);
            s2[((size_t)b * CIN + c) * (T0 / 4) + t0 / 4 + tx] = v;
        }
    }
}

// ---------------- FFT: 2 real rows packed per complex FFT, 8 rows/block ----------------
template<int LOGT>
__global__ __launch_bounds__(256) void fft_amps(const float* __restrict__ xm,
                                                float* __restrict__ part, int pad) {
    constexpr int T = 1 << LOGT;
    constexpr int F = T / 2;
    __shared__ float re[T], im[T];
    __shared__ float twc[F], tws[F];
    __shared__ float acc[F + 1];
    int tid = threadIdx.x;
    for (int j = tid; j < F; j += 256) {
        float s, c;
        sincosf(-6.283185307179586f * (float)j / (float)T, &s, &c);
        twc[j] = c; tws[j] = s;
    }
    for (int i = tid; i <= F; i += 256) acc[i] = 0.f;
    __syncthreads();

    int rowbase = blockIdx.x * 8;
    for (int pr = 0; pr < 4; pr++) {
        const float* row0 = xm + (size_t)(rowbase + 2 * pr) * T;
        const float* row1 = row0 + T;
        for (int j = tid; j < T; j += 256) {
            int rv = (int)(__brev((unsigned)j) >> (32 - LOGT));
            re[rv] = row0[j];
            im[rv] = row1[j];
        }
        __syncthreads();
        for (int s = 1; s <= LOGT; s++) {
            int mh = 1 << (s - 1);
            for (int bf = tid; bf < T / 2; bf += 256) {
                int k  = bf & (mh - 1);
                int g  = bf >> (s - 1);
                int i1 = (g << s) + k;
                int i2 = i1 + mh;
                int twi = k << (LOGT - s);
                float wr = twc[twi], wi = tws[twi];
                float xr = re[i2], xi = im[i2];
                float tr = wr * xr - wi * xi;
                float ti = wr * xi + wi * xr;
                float ur = re[i1], ui = im[i1];
                re[i1] = ur + tr; im[i1] = ui + ti;
                re[i2] = ur - tr; im[i2] = ui - ti;
            }
            __syncthreads();
        }
        for (int f = tid; f <= F; f += 256) {
            if (f >= 1) {
                int mf = T - f;
                float rf = re[f], imf = im[f];
                float rm = re[mf], imm = im[mf];
                float m0 = sqrtf((rf + rm) * (rf + rm) + (imf - imm) * (imf - imm));
                float m1 = sqrtf((imf + imm) * (imf + imm) + (rf - rm) * (rf - rm));
                acc[f] += 0.5f * (m0 + m1);
            }
        }
        __syncthreads();
    }
    for (int f = tid; f <= F; f += 256)
        part[(size_t)blockIdx.x * pad + f] = acc[f];
}

// ---------------- deterministic reduce of partials -> amps (mean) ----------------
__global__ __launch_bounds__(256) void reduce_amps(const float* __restrict__ parts,
                                                   float* __restrict__ amps) {
    const int PADs[3] = {520, 264, 136};
    const int Fs[3]   = {513, 257, 129};
    const size_t POFF[3] = {0, (size_t)1024 * 520, (size_t)1024 * 520 + (size_t)1024 * 264};
    const int AOFF[3] = {0, 520, 780};
    int s  = blockIdx.y;
    int fl = threadIdx.x & 63;
    int rg = threadIdx.x >> 6;
    int f  = blockIdx.x * 64 + fl;
    bool valid = f < Fs[s];
    const float* base = parts + POFF[s];
    int pad = PADs[s];
    float sum = 0.f;
    if (valid)
        for (int r = rg; r < 1024; r += 4) sum += base[(size_t)r * pad + f];
    __shared__ float red[256];
    red[threadIdx.x] = sum;
    __syncthreads();
    if (rg == 0 && valid) {
        float tot = red[fl] + red[fl + 64] + red[fl + 128] + red[fl + 192];
        amps[AOFF[s] + f] = tot * (1.f / 8192.f);
    }
}

// ---------------- top-3: one block per scale, deterministic ----------------
__device__ inline void ins3(float v, int i, float& b0, int& c0,
                            float& b1, int& c1, float& b2, int& c2) {
    bool g0 = (v > b0) || (v == b0 && i < c0);
    bool g1 = (v > b1) || (v == b1 && i < c1);
    bool g2 = (v > b2) || (v == b2 && i < c2);
    if (g0)      { b2 = b1; c2 = c1; b1 = b0; c1 = c0; b0 = v; c0 = i; }
    else if (g1) { b2 = b1; c2 = c1; b1 = v; c1 = i; }
    else if (g2) { b2 = v; c2 = i; }
}

__global__ __launch_bounds__(256) void meta_topk(const float* __restrict__ amps,
                          const float* __restrict__ slog,
                          int* __restrict__ freqs, float* __restrict__ wk,
                          float* __restrict__ sw) {
    __shared__ float sv[12];
    __shared__ int   si[12];
    const int offs[3] = {0, 520, 780};
    const int Fs[3]   = {513, 257, 129};
    int m = blockIdx.x;
    int tid = threadIdx.x, lane = tid & 63, wv = tid >> 6;
    const float* a = amps + offs[m];
    int F = Fs[m];
    float b0 = -1e30f, b1 = -1e30f, b2 = -1e30f;
    int   c0 = 0x7fffffff, c1 = 0x7fffffff, c2 = 0x7fffffff;
    for (int i = tid; i < F; i += 256)
        ins3(a[i], i, b0, c0, b1, c1, b2, c2);
#pragma unroll
    for (int d = 1; d < 64; d <<= 1) {
        float o0 = __shfl_xor(b0, d), o1 = __shfl_xor(b1, d), o2 = __shfl_xor(b2, d);
        int   i0 = __shfl_xor(c0, d), i1 = __shfl_xor(c1, d), i2 = __shfl_xor(c2, d);
        ins3(o0, i0, b0, c0, b1, c1, b2, c2);
        ins3(o1, i1, b0, c0, b1, c1, b2, c2);
        ins3(o2, i2, b0, c0, b1, c1, b2, c2);
    }
    if (lane == 0) {
        sv[wv * 3 + 0] = b0; si[wv * 3 + 0] = c0;
        sv[wv * 3 + 1] = b1; si[wv * 3 + 1] = c1;
        sv[wv * 3 + 2] = b2; si[wv * 3 + 2] = c2;
    }
    __syncthreads();
    if (tid == 0) {
        float d0 = sv[0], d1 = sv[1], d2 = sv[2];
        int   e0 = si[0], e1 = si[1], e2 = si[2];
        for (int q = 3; q < 12; q++) ins3(sv[q], si[q], d0, e0, d1, e1, d2, e2);
        int fr[3] = {max(1, e0), max(1, e1), max(1, e2)};
        float av[3] = {a[fr[0]], a[fr[1]], a[fr[2]]};
        float mx = fmaxf(av[0], fmaxf(av[1], av[2]));
        float x0 = expf(av[0] - mx), x1 = expf(av[1] - mx), x2 = expf(av[2] - mx);
        float inv = 1.f / (x0 + x1 + x2);
        freqs[m * 3 + 0] = fr[0]; freqs[m * 3 + 1] = fr[1]; freqs[m * 3 + 2] = fr[2];
        wk[m * 3 + 0] = x0 * inv; wk[m * 3 + 1] = x1 * inv; wk[m * 3 + 2] = x2 * inv;
        if (m == 0) {
            float s0 = slog[0], s1 = slog[1], s2 = slog[2];
            float mx2 = fmaxf(s0, fmaxf(s1, s2));
            float e0b = expf(s0 - mx2), e1b = expf(s1 - mx2), e2b = expf(s2 - mx2);
            float inv2 = 3.f / (e0b + e1b + e2b);
            sw[0] = e0b * inv2; sw[1] = e1b * inv2; sw[2] = e2b * inv2;
        }
    }
}

// ---------------- prep: w2ot[o][c^((o&7)<<3)] = sum_h w_ch[o,h]*pw_w[h,c] (bf16) ----------------
__global__ __launch_bounds__(256) void prep_w2(const float* __restrict__ w_ch,
        const float* __restrict__ pw_w, const float* __restrict__ pw_b,
        unsigned short* __restrict__ w2ot, float* __restrict__ pbs) {
    int tid = threadIdx.x;
    if (blockIdx.x == 64) {
        if (tid < 128) {
            float pb = 0.f, s = 0.f;
            for (int h = 0; h < HID; h++) {
                float w = w_ch[tid * HID + h];
                pb += w * pw_b[h]; s += w;
            }
            pbs[tid] = pb; pbs[128 + tid] = s;
        }
        return;
    }
    int idx = blockIdx.x * 256 + tid;
    int c = idx >> 7, o = idx & 127;
    float acc = 0.f;
    for (int h = 0; h < HID; h++) acc += w_ch[o * HID + h] * pw_w[h * CIN + c];
    w2ot[o * 128 + (c ^ ((o & 7) << 3))] = f2bf(acc);
}

// ---------------- prep: w_t -> bf16 + row sums ----------------
__global__ __launch_bounds__(256) void prep_wt(const float* __restrict__ wt0,
        const float* __restrict__ wt1, const float* __restrict__ wt2,
        unsigned short* __restrict__ wtb, float* __restrict__ wsum) {
    int wid = blockIdx.x * 4 + (threadIdx.x >> 6);
    int lane = threadIdx.x & 63;
    const float* src; int T, p, m; size_t off;
    if (wid < 192)      { m = 0; p = wid;       src = wt0; T = 1024; off = 0; }
    else if (wid < 384) { m = 1; p = wid - 192; src = wt1; T = 512;  off = (size_t)192 * 1024; }
    else                { m = 2; p = wid - 384; src = wt2; T = 256;  off = (size_t)192 * 1024 + (size_t)192 * 512; }
    const float* row = src + (size_t)p * T;
    unsigned short* dst = wtb + off + (size_t)p * T;
    float s = 0.f;
    for (int j = lane; j < T; j += 64) { float v = row[j]; s += v; dst[j] = f2bf(v); }
#pragma unroll
    for (int d = 1; d < 64; d <<= 1) s += __shfl_xor(s, d);
    if (lane == 0) wsum[m * 192 + p] = s;
}

// ---------------- depthwise mix: one wave per channel, pair-ILP, masked taps ----------------
template<int T>
__global__ __launch_bounds__(256) void dwmix_k(const float* __restrict__ xm,
        const float* __restrict__ dw_w, const float* __restrict__ dw_b,
        const int* __restrict__ freqs, const float* __restrict__ wkbuf, int m,
        unsigned short* __restrict__ dwmix) {
    constexpr int CPB = 4;
    constexpr int RS  = T + 8;                 // padded row stride
    constexpr int NP  = T / 128;               // pair-iterations per thread
    __shared__ float xs[CPB * RS];
    __shared__ unsigned short msk[3 * T];
    int tid = threadIdx.x;
    int b = blockIdx.y;
    int c0 = blockIdx.x * CPB;

    int pk[3]; float wkv[3];
#pragma unroll
    for (int k = 0; k < 3; k++) {
        int f = freqs[m * 3 + k];
        pk[k] = T / f;
        wkv[k] = wkbuf[m * 3 + k];
    }
    // stage CPB rows (coalesced float4) + zero slot at row offset T
    const float* src = xm + ((size_t)b * CIN + c0) * T;
    for (int i = tid; i < CPB * (T / 4); i += 256) {
        int ch = i / (T / 4), seg = i - ch * (T / 4);
        *(float4*)&xs[ch * RS + seg * 4] = *(const float4*)&src[(size_t)ch * T + seg * 4];
    }
    if (tid < CPB) xs[tid * RS + T] = 0.f;
    // 9-bit validity masks per (k, l)
    for (int l = tid; l < T; l += 256) {
#pragma unroll
        for (int k = 0; k < 3; k++) {
            int p = pk[k];
            int rows = (T + p - 1) / p;
            int r = l / p, cc = l - r * p;
            unsigned mm = 0; int q = 0;
#pragma unroll
            for (int dr = -1; dr <= 1; dr++)
#pragma unroll
                for (int dc = -1; dc <= 1; dc++, q++) {
                    int rr2 = r + dr, c2 = cc + dc;
                    int pos = l + dr * p + dc;
                    if (rr2 >= 0 && rr2 < rows && c2 >= 0 && c2 < p && pos < T)
                        mm |= 1u << q;
                }
            msk[k * T + l] = (unsigned short)mm;
        }
    }
    __syncthreads();

    int ch = tid >> 6, j = tid & 63;           // one wave = one channel
    int c = c0 + ch;
    float w9[9];
#pragma unroll
    for (int q = 0; q < 9; q++) w9[q] = dw_w[c * 9 + q];
    float bias = dw_b[c];
    int cb = ch * RS;
    unsigned short* outp = dwmix + ((size_t)b * CIN + c) * T;

    for (int i = 0; i < NP; i++) {
        int l0 = i * 128 + 2 * j, l1 = l0 + 1;
        float s0 = bias, s1 = bias;
#pragma unroll
        for (int k = 0; k < 3; k++) {
            int p = pk[k];
            unsigned m0 = msk[k * T + l0];
            unsigned m1 = msk[k * T + l1];
            float a0 = 0.f, a1 = 0.f;
            int q = 0;
#pragma unroll
            for (int dr = -1; dr <= 1; dr++) {
                int r0 = l0 + dr * p, r1 = l1 + dr * p;
#pragma unroll
                for (int dc = -1; dc <= 1; dc++, q++) {
                    int i0 = ((m0 >> q) & 1) ? (r0 + dc) : T;
                    int i1 = ((m1 >> q) & 1) ? (r1 + dc) : T;
                    a0 += w9[q] * xs[cb + i0];
                    a1 += w9[q] * xs[cb + i1];
                }
            }
            s0 += wkv[k] * a0; s1 += wkv[k] * a1;
        }
        unsigned pk2 = (unsigned)f2bf(s0) | ((unsigned)f2bf(s1) << 16);
        *(unsigned*)&outp[l0] = pk2;
    }
}

// ---------------- tp GEMM: C[192][8192] = A[192][T] * B[8192][T]^T (bf16 MFMA) ----------------
template<int T>
__global__ __launch_bounds__(256) void tp_gemm(const unsigned short* __restrict__ A,
        const unsigned short* __restrict__ B, unsigned short* __restrict__ C) {
    __shared__ __align__(16) unsigned short As[64 * 72];
    __shared__ __align__(16) unsigned short Bs[64 * 72];
    int tid = threadIdx.x;
    int lane = tid & 63, wave = tid >> 6;
    int wm = (wave >> 1) * 32, wn = (wave & 1) * 32;
    int p0 = blockIdx.x * 64, n0 = blockIdx.y * 64;
    f32x4 acc[2][2];
#pragma unroll
    for (int i = 0; i < 2; i++)
#pragma unroll
        for (int j = 0; j < 2; j++) acc[i][j] = (f32x4){0.f, 0.f, 0.f, 0.f};

    int r = tid >> 2, seg = tid & 3;
    const unsigned short* ga = A + (size_t)(p0 + r) * T + seg * 16;
    const unsigned short* gb = B + (size_t)(n0 + r) * T + seg * 16;
    unsigned short* la = &As[r * 72 + seg * 16];
    unsigned short* lb = &Bs[r * 72 + seg * 16];
    int fr = lane & 15, fk = (lane >> 4) * 8;

    for (int k0 = 0; k0 < T; k0 += 64) {
        __syncthreads();
        *(uint4*)la       = *(const uint4*)ga;
        *(uint4*)(la + 8) = *(const uint4*)(ga + 8);
        *(uint4*)lb       = *(const uint4*)gb;
        *(uint4*)(lb + 8) = *(const uint4*)(gb + 8);
        ga += 64; gb += 64;
        __syncthreads();
#pragma unroll
        for (int ks = 0; ks < 2; ks++) {
            int ko = ks * 32 + fk;
            s16x8 a0 = *(const s16x8*)&As[(wm + fr) * 72 + ko];
            s16x8 a1 = *(const s16x8*)&As[(wm + 16 + fr) * 72 + ko];
            s16x8 b0 = *(const s16x8*)&Bs[(wn + fr) * 72 + ko];
            s16x8 b1 = *(const s16x8*)&Bs[(wn + 16 + fr) * 72 + ko];
            acc[0][0] = __builtin_amdgcn_mfma_f32_16x16x32_bf16(a0, b0, acc[0][0], 0, 0, 0);
            acc[0][1] = __builtin_amdgcn_mfma_f32_16x16x32_bf16(a0, b1, acc[0][1], 0, 0, 0);
            acc[1][0] = __builtin_amdgcn_mfma_f32_16x16x32_bf16(a1, b0, acc[1][0], 0, 0, 0);
            acc[1][1] = __builtin_amdgcn_mfma_f32_16x16x32_bf16(a1, b1, acc[1][1], 0, 0, 0);
        }
    }
    int crow = (lane >> 4) * 4, ccol = lane & 15;
#pragma unroll
    for (int i = 0; i < 2; i++)
#pragma unroll
        for (int j = 0; j < 2; j++) {
            int col = n0 + wn + j * 16 + ccol;
#pragma unroll
            for (int reg = 0; reg < 4; reg++) {
                int row = p0 + wm + i * 16 + crow + reg;
                C[(size_t)row * 8192 + col] = f2bf(acc[i][j][reg]);
            }
        }
}

// ---------------- final: out = residual + sum_m sw_m*(W2@tp_m + biases) ----------------
__global__ __launch_bounds__(256) void final_out(const float* __restrict__ x,
        const unsigned short* __restrict__ tp, const unsigned short* __restrict__ w2ot,
        const float* __restrict__ pbs, const float* __restrict__ wsum,
        const float* __restrict__ bt0, const float* __restrict__ bt1,
        const float* __restrict__ bt2, const float* __restrict__ b_ch,
        const float* __restrict__ swb, float* __restrict__ out) {
    __shared__ unsigned short w2s[128 * 128];   // [o][c-swizzled] bf16, 32 KB
    __shared__ float tpsS[32][128];             // weighted tp rows, 16 KB
    __shared__ float wsS[32], btS[32];
    const size_t TPPL = (size_t)192 * 8192;
    int tid = threadIdx.x;
    int r0 = blockIdx.x * 32;
    float sw0 = swb[0], sw1 = swb[1], sw2 = swb[2];

    // stage w2 (linear copy; swizzle pre-baked by prep_w2)
#pragma unroll
    for (int i = 0; i < 8; i++)
        ((uint4*)w2s)[i * 256 + tid] = ((const uint4*)w2ot)[i * 256 + tid];
    // stage 32 rows x 128 c of sw-weighted tp (3 scales fused), uint4 loads
#pragma unroll
    for (int it = 0; it < 2; it++) {
        int idx = tid + it * 256;                // 512 = 32 rows x 16 uint4
        int rr = idx >> 4, u = idx & 15;
        int r = r0 + rr;
        int b2 = r / 192, p2 = r - b2 * 192;
        size_t base = (size_t)p2 * 8192 + (size_t)b2 * 128 + u * 8;
        uint4 q0 = *(const uint4*)&tp[base];
        uint4 q1 = *(const uint4*)&tp[TPPL + base];
        uint4 q2 = *(const uint4*)&tp[2 * TPPL + base];
        const unsigned* a0 = (const unsigned*)&q0;
        const unsigned* a1 = (const unsigned*)&q1;
        const unsigned* a2 = (const unsigned*)&q2;
        float o8[8];
#pragma unroll
        for (int w = 0; w < 4; w++) {
            o8[2 * w]     = sw0 * bf2f(a0[w] & 0xffff) + sw1 * bf2f(a1[w] & 0xffff)
                          + sw2 * bf2f(a2[w] & 0xffff);
            o8[2 * w + 1] = sw0 * bf2f(a0[w] >> 16) + sw1 * bf2f(a1[w] >> 16)
                          + sw2 * bf2f(a2[w] >> 16);
        }
        *(float4*)&tpsS[rr][u * 8]     = *(float4*)&o8[0];
        *(float4*)&tpsS[rr][u * 8 + 4] = *(float4*)&o8[4];
    }
    if (tid < 32) {
        int r = r0 + tid;
        int b2 = r / 192, p = r - b2 * 192;
        wsS[tid] = sw0 * wsum[p] + sw1 * wsum[192 + p] + sw2 * wsum[384 + p];
        btS[tid] = sw0 * bt0[p] + sw1 * bt1[p] + sw2 * bt2[p];
    }
    __syncthreads();

    int o = tid & 127, half = tid >> 7;
    int rbase = half * 16;
    float pbv  = pbs[o];
    float schv = pbs[128 + o];
    float bchv = (sw0 + sw1 + sw2) * b_ch[o];
    float acc[16];
#pragma unroll
    for (int rr = 0; rr < 16; rr++) acc[rr] = 0.f;

#pragma unroll 2
    for (int cb8 = 0; cb8 < 16; cb8++) {
        uint4 wv = *(const uint4*)&w2s[o * 128 + ((cb8 ^ (o & 7)) << 3)];
        const unsigned* aw = (const unsigned*)&wv;
        float wf[8];
#pragma unroll
        for (int w = 0; w < 4; w++) {
            wf[2 * w]     = bf2f(aw[w] & 0xffff);
            wf[2 * w + 1] = bf2f(aw[w] >> 16);
        }
        int cc = cb8 * 8;
#pragma unroll
        for (int rr = 0; rr < 16; rr++) {
            const float* tr = &tpsS[rbase + rr][cc];
            float4 t0 = *(const float4*)tr;
            float4 t1 = *(const float4*)(tr + 4);
            acc[rr] += wf[0] * t0.x + wf[1] * t0.y + wf[2] * t0.z + wf[3] * t0.w
                     + wf[4] * t1.x + wf[5] * t1.y + wf[6] * t1.z + wf[7] * t1.w;
        }
    }
#pragma unroll
    for (int rr = 0; rr < 16; rr++) {
        int r = r0 + rbase + rr;
        int b2 = r / 192, p = r - b2 * 192;
        float res = x[((size_t)b2 * T0 + (T0 - PRED) + p) * CIN + o];
        out[(size_t)r * TGT + o] = res + acc[rr] + pbv * wsS[rbase + rr]
                                 + schv * btS[rbase + rr] + bchv;
    }
}

extern "C" void kernel_launch(void* const* d_in, const int* in_sizes, int n_in,
                              void* d_out, int out_size, void* d_ws, size_t ws_size,
                              hipStream_t stream) {
    const float* x    = (const float*)d_in[0];
    const float* dw_w = (const float*)d_in[1];
    const float* dw_b = (const float*)d_in[2];
    const float* pw_w = (const float*)d_in[3];
    const float* pw_b = (const float*)d_in[4];
    const float* wt0  = (const float*)d_in[5];
    const float* bt0  = (const float*)d_in[6];
    const float* wt1  = (const float*)d_in[7];
    const float* bt1  = (const float*)d_in[8];
    const float* wt2  = (const float*)d_in[9];
    const float* bt2  = (const float*)d_in[10];
    const float* w_ch = (const float*)d_in[11];
    const float* b_ch = (const float*)d_in[12];
    const float* slog = (const float*)d_in[13];
    float* out = (float*)d_out;
    float* ws  = (float*)d_ws;

    float* xct   = ws + XCT_OFF;
    float* s1b   = ws + S1_OFF;
    float* s2b   = ws + S2_OFF;
    float* parts = ws + P0_OFF;
    float* ampsb = ws + AMPS_OFF;
    int*   freqs = (int*)(ws + META_OFF);
    float* wkb   = ws + META_OFF + 16;
    float* swb   = ws + META_OFF + 32;
    unsigned short* w2tb  = (unsigned short*)(ws + W2T_OFF);
    float* pbs   = ws + PBS_OFF;
    float* wsumb = ws + WSUM_OFF;
    unsigned short* wtb   = (unsigned short*)(ws + WTB_OFF);
    unsigned short* dwm   = (unsigned short*)(ws + DWMIX_OFF);
    unsigned short* tpb   = (unsigned short*)(ws + TP_OFF);

    const size_t WT1O = (size_t)192 * 1024;
    const size_t WT2O = WT1O + (size_t)192 * 512;
    const size_t TPPL = (size_t)192 * 8192;

    front<<<dim3(32, 4, NB), dim3(32, 8, 1), 0, stream>>>(x, xct, s1b, s2b);

    fft_amps<10><<<1024, 256, 0, stream>>>(xct, parts, 520);
    fft_amps<9><<<1024, 256, 0, stream>>>(s1b, parts + (size_t)1024 * 520, 264);
    fft_amps<8><<<1024, 256, 0, stream>>>(s2b, parts + (size_t)1024 * 520 + (size_t)1024 * 264, 136);
    reduce_amps<<<dim3(9, 3), 256, 0, stream>>>(parts, ampsb);
    meta_topk<<<3, 256, 0, stream>>>(ampsb, slog, freqs, wkb, swb);

    prep_w2<<<65, 256, 0, stream>>>(w_ch, pw_w, pw_b, w2tb, pbs);
    prep_wt<<<144, 256, 0, stream>>>(wt0, wt1, wt2, wtb, wsumb);

    // scale 0 (T=1024)
    dwmix_k<1024><<<dim3(32, NB), 256, 0, stream>>>(xct, dw_w, dw_b, freqs, wkb, 0, dwm);
    tp_gemm<1024><<<dim3(3, 128), 256, 0, stream>>>(wtb, dwm, tpb);
    // scale 1 (T=512)
    dwmix_k<512><<<dim3(32, NB), 256, 0, stream>>>(s1b, dw_w, dw_b, freqs, wkb, 1, dwm);
    tp_gemm<512><<<dim3(3, 128), 256, 0, stream>>>(wtb + WT1O, dwm, tpb + TPPL);
    // scale 2 (T=256)
    dwmix_k<256><<<dim3(32, NB), 256, 0, stream>>>(s2b, dw_w, dw_b, freqs, wkb, 2, dwm);
    tp_gemm<256><<<dim3(3, 128), 256, 0, stream>>>(wtb + WT2O, dwm, tpb + 2 * TPPL);

    final_out<<<384, 256, 0, stream>>>(x, tpb, w2tb, pbs, wsumb,
                                       bt0, bt1, bt2, b_ch, swb, out);
}

// Round 5
// 257.262 us; speedup vs baseline: 3.8694x; 1.3433x over previous
//
#include <hip/hip_runtime.h>
#include <math.h>

#define NB   64
#define T0   1024
#define CIN  128
#define HID  256
#define TGT  128
#define PRED 192
#define NROWS (NB*CIN)

typedef __attribute__((ext_vector_type(4))) float f32x4;
typedef __attribute__((ext_vector_type(8))) short s16x8;

// ---------------- workspace layout (float offsets) ----------------
static const size_t XCT_OFF    = 0;          // [64][128][1024] f32
static const size_t S1_OFF     = 8388608;    // [64][128][512]
static const size_t S2_OFF     = 12582912;   // [64][128][256]
static const size_t P0_OFF     = 14680064;   // [1024][520]
static const size_t P1_OFF     = 15212544;   // [1024][264]
static const size_t P2_OFF     = 15482880;   // [1024][136]
static const size_t PARTS2_OFF = 15622144;   // [3][16][520] row-split partials
static const size_t META_OFF   = 15647104;   // 64: freqs int[9]@0, wk f32[9]@16, sw f32[3]@32
static const size_t W2T_OFF    = 15647168;   // [128 o][128 c-swizzled] bf16 (8192 floats)
static const size_t PBS_OFF    = 15655360;   // Pb[128], S_ch[128] f32
static const size_t WSUM_OFF   = 15655616;   // [3][192] f32
static const size_t WTB_OFF    = 15656192;   // bf16 w_t (172032 floats)
static const size_t DWMIX_OFF  = 15828224;   // bf16 [8192][T] (4194304 floats)
static const size_t TP_OFF     = 20022528;   // bf16 [3][192][8192] (2359296 floats)
// end = 22381824 floats = 89.5 MB

__device__ inline unsigned short f2bf(float x) {
    union { float f; unsigned u; } v; v.f = x;
    unsigned r = (v.u + 0x7FFFu + ((v.u >> 16) & 1u)) >> 16;
    return (unsigned short)r;
}
__device__ inline float bf2f(unsigned short u) {
    union { unsigned u; float f; } v; v.u = ((unsigned)u) << 16;
    return v.f;
}

// ---------------- fused: transpose x[B,T,C]->xct[B,C,T] + pool1 + pool2 ----------------
__global__ __launch_bounds__(256) void front(const float* __restrict__ x,
        float* __restrict__ xct, float* __restrict__ s1, float* __restrict__ s2) {
    __shared__ float tile[32][33];
    int b = blockIdx.z;
    int t0 = blockIdx.x * 32, c0 = blockIdx.y * 32;
    int tx = threadIdx.x, ty = threadIdx.y;       // 32 x 8
#pragma unroll
    for (int i = 0; i < 4; i++) {
        int t = t0 + ty + i * 8, c = c0 + tx;
        tile[ty + i * 8][tx] = x[((size_t)b * T0 + t) * CIN + c];
    }
    __syncthreads();
#pragma unroll
    for (int i = 0; i < 4; i++) {
        int c = c0 + ty + i * 8, cc = ty + i * 8;
        xct[((size_t)b * CIN + c) * T0 + t0 + tx] = tile[tx][cc];
        if (tx < 16) {
            float v = 0.5f * (tile[2 * tx][cc] + tile[2 * tx + 1][cc]);
            s1[((size_t)b * CIN + c) * (T0 / 2) + t0 / 2 + tx] = v;
        }
        if (tx < 8) {
            float v = 0.25f * (tile[4 * tx][cc] + tile[4 * tx + 1][cc]
                             + tile[4 * tx + 2][cc] + tile[4 * tx + 3][cc]);
            s2[((size_t)b * CIN + c) * (T0 / 4) + t0 / 4 + tx] = v;
        }
    }
}

// ---------------- FFT: 2 real rows per complex FFT, double-stage radix-2 in LDS ----------------
// phys(i) = i + (i>>5): +1 float pad per 32 — makes stride-4 group access and
// stride-32 twiddle reads bank-conflict-free.
#define PHYS(i) ((i) + ((i) >> 5))
template<int LOGT>
__global__ __launch_bounds__(256) void fft_amps(const float* __restrict__ xm,
                                                float* __restrict__ part, int pad) {
    constexpr int T = 1 << LOGT;
    constexpr int F = T / 2;
    __shared__ float re[T + (T >> 5)], im[T + (T >> 5)];
    __shared__ float twc[F + (F >> 5)], tws[F + (F >> 5)];
    __shared__ float acc[F + 1];
    int tid = threadIdx.x;
    for (int j = tid; j < F; j += 256) {
        float s, c;
        sincosf(-6.283185307179586f * (float)j / (float)T, &s, &c);
        twc[PHYS(j)] = c; tws[PHYS(j)] = s;
    }
    for (int i = tid; i <= F; i += 256) acc[i] = 0.f;
    __syncthreads();

    int rowbase = blockIdx.x * 8;
    for (int pr = 0; pr < 4; pr++) {
        const float* row0 = xm + (size_t)(rowbase + 2 * pr) * T;
        const float* row1 = row0 + T;
        for (int j = tid; j < T; j += 256) {
            int rv = (int)(__brev((unsigned)j) >> (32 - LOGT));
            re[PHYS(rv)] = row0[j];
            im[PHYS(rv)] = row1[j];
        }
        __syncthreads();
        // double stages: two radix-2 stages per LDS round-trip
        for (int s = 1; s + 1 <= LOGT; s += 2) {
            int mh = 1 << (s - 1);
            if (tid < T / 4) {
                int k  = tid & (mh - 1);
                int gq = tid >> (s - 1);
                int i0 = (gq << (s + 1)) + k;
                int iA = PHYS(i0), iB = PHYS(i0 + mh);
                int iC = PHYS(i0 + 2 * mh), iD = PHYS(i0 + 3 * mh);
                int t1 = PHYS(k << (LOGT - s));
                int t2 = PHYS(k << (LOGT - s - 1));
                int t3 = PHYS((k + mh) << (LOGT - s - 1));
                float w1r = twc[t1], w1i = tws[t1];
                float w2r = twc[t2], w2i = tws[t2];
                float w3r = twc[t3], w3i = tws[t3];
                float ar = re[iA], ai = im[iA];
                float br = re[iB], bi = im[iB];
                float cr = re[iC], ci = im[iC];
                float dr = re[iD], di = im[iD];
                // stage s
                float tbr = w1r * br - w1i * bi, tbi = w1r * bi + w1i * br;
                float tdr = w1r * dr - w1i * di, tdi = w1r * di + w1i * dr;
                float v0r = ar + tbr, v0i = ai + tbi;
                float v1r = ar - tbr, v1i = ai - tbi;
                float v2r = cr + tdr, v2i = ci + tdi;
                float v3r = cr - tdr, v3i = ci - tdi;
                // stage s+1
                float t2r = w2r * v2r - w2i * v2i, t2i = w2r * v2i + w2i * v2r;
                float t3r = w3r * v3r - w3i * v3i, t3i = w3r * v3i + w3i * v3r;
                re[iA] = v0r + t2r; im[iA] = v0i + t2i;
                re[iC] = v0r - t2r; im[iC] = v0i - t2i;
                re[iB] = v1r + t3r; im[iB] = v1i + t3i;
                re[iD] = v1r - t3r; im[iD] = v1i - t3i;
            }
            __syncthreads();
        }
        if (LOGT & 1) {                      // leftover single stage s = LOGT
            constexpr int s = LOGT;
            int mh = 1 << (s - 1);
            if (tid < T / 2) {
                int k  = tid & (mh - 1);
                int i1 = PHYS(tid);          // g==0 for the last stage (mh=T/2)
                int i2 = PHYS(tid + mh);
                int tw = PHYS(k);            // k << (LOGT-s) == k
                float wr = twc[tw], wi = tws[tw];
                float xr = re[i2], xi = im[i2];
                float tr = wr * xr - wi * xi;
                float ti = wr * xi + wi * xr;
                float ur = re[i1], ui = im[i1];
                re[i1] = ur + tr; im[i1] = ui + ti;
                re[i2] = ur - tr; im[i2] = ui - ti;
            }
            __syncthreads();
        }
        // unpack two real spectra
        for (int f = tid; f <= F; f += 256) {
            if (f >= 1) {
                int mf = T - f;
                float rf = re[PHYS(f)], imf = im[PHYS(f)];
                float rm = re[PHYS(mf)], imm = im[PHYS(mf)];
                float m0 = sqrtf((rf + rm) * (rf + rm) + (imf - imm) * (imf - imm));
                float m1 = sqrtf((imf + imm) * (imf + imm) + (rf - rm) * (rf - rm));
                acc[f] += 0.5f * (m0 + m1);
            }
        }
        __syncthreads();
    }
    for (int f = tid; f <= F; f += 256)
        part[(size_t)blockIdx.x * pad + f] = acc[f];
}

// ---------------- stage A: sum 64 rows per block -> parts2[s][16][520] ----------------
__global__ __launch_bounds__(256) void reduce_partA(const float* __restrict__ parts,
                                                    float* __restrict__ parts2) {
    const int PADs[3] = {520, 264, 136};
    const int Fs[3]   = {513, 257, 129};
    const size_t POFF[3] = {0, (size_t)1024 * 520, (size_t)1024 * 520 + (size_t)1024 * 264};
    int s  = blockIdx.y;
    int rs = blockIdx.z;
    int fl = threadIdx.x & 63;
    int rg = threadIdx.x >> 6;
    int f  = blockIdx.x * 64 + fl;
    bool valid = f < Fs[s];
    const float* base = parts + POFF[s];
    int pad = PADs[s];
    float sum = 0.f;
    if (valid) {
        int r0 = rs * 64 + rg * 16;
#pragma unroll
        for (int i = 0; i < 16; i++) sum += base[(size_t)(r0 + i) * pad + f];
    }
    __shared__ float red[256];
    red[threadIdx.x] = sum;
    __syncthreads();
    if (rg == 0 && valid) {
        float tot = red[fl] + red[fl + 64] + red[fl + 128] + red[fl + 192];
        parts2[(size_t)(s * 16 + rs) * 520 + f] = tot;
    }
}

__device__ inline float sum16(const float* __restrict__ p2, int m, int f) {
    const float* b = p2 + (size_t)m * 16 * 520 + f;
    float s = 0.f;
#pragma unroll
    for (int r = 0; r < 16; r++) s += b[r * 520];
    return s;
}

// ---------------- top-3: one block per scale, deterministic ----------------
__device__ inline void ins3(float v, int i, float& b0, int& c0,
                            float& b1, int& c1, float& b2, int& c2) {
    bool g0 = (v > b0) || (v == b0 && i < c0);
    bool g1 = (v > b1) || (v == b1 && i < c1);
    bool g2 = (v > b2) || (v == b2 && i < c2);
    if (g0)      { b2 = b1; c2 = c1; b1 = b0; c1 = c0; b0 = v; c0 = i; }
    else if (g1) { b2 = b1; c2 = c1; b1 = v; c1 = i; }
    else if (g2) { b2 = v; c2 = i; }
}

__global__ __launch_bounds__(256) void meta_topk(const float* __restrict__ parts2,
                          const float* __restrict__ slog,
                          int* __restrict__ freqs, float* __restrict__ wk,
                          float* __restrict__ sw) {
    __shared__ float sv[12];
    __shared__ int   si[12];
    const int Fs[3] = {513, 257, 129};
    int m = blockIdx.x;
    int tid = threadIdx.x, lane = tid & 63, wv = tid >> 6;
    int F = Fs[m];
    float b0 = -1e30f, b1 = -1e30f, b2 = -1e30f;
    int   c0 = 0x7fffffff, c1 = 0x7fffffff, c2 = 0x7fffffff;
    for (int i = tid; i < F; i += 256) {
        float v = (i == 0) ? 0.f : sum16(parts2, m, i) * (1.f / 8192.f);
        ins3(v, i, b0, c0, b1, c1, b2, c2);
    }
#pragma unroll
    for (int d = 1; d < 64; d <<= 1) {
        float o0 = __shfl_xor(b0, d), o1 = __shfl_xor(b1, d), o2 = __shfl_xor(b2, d);
        int   i0 = __shfl_xor(c0, d), i1 = __shfl_xor(c1, d), i2 = __shfl_xor(c2, d);
        ins3(o0, i0, b0, c0, b1, c1, b2, c2);
        ins3(o1, i1, b0, c0, b1, c1, b2, c2);
        ins3(o2, i2, b0, c0, b1, c1, b2, c2);
    }
    if (lane == 0) {
        sv[wv * 3 + 0] = b0; si[wv * 3 + 0] = c0;
        sv[wv * 3 + 1] = b1; si[wv * 3 + 1] = c1;
        sv[wv * 3 + 2] = b2; si[wv * 3 + 2] = c2;
    }
    __syncthreads();
    if (tid == 0) {
        float d0 = sv[0], d1 = sv[1], d2 = sv[2];
        int   e0 = si[0], e1 = si[1], e2 = si[2];
        for (int q = 3; q < 12; q++) ins3(sv[q], si[q], d0, e0, d1, e1, d2, e2);
        int fr[3] = {max(1, e0), max(1, e1), max(1, e2)};
        float av[3];
#pragma unroll
        for (int i = 0; i < 3; i++) av[i] = sum16(parts2, m, fr[i]) * (1.f / 8192.f);
        float mx = fmaxf(av[0], fmaxf(av[1], av[2]));
        float x0 = expf(av[0] - mx), x1 = expf(av[1] - mx), x2 = expf(av[2] - mx);
        float inv = 1.f / (x0 + x1 + x2);
        freqs[m * 3 + 0] = fr[0]; freqs[m * 3 + 1] = fr[1]; freqs[m * 3 + 2] = fr[2];
        wk[m * 3 + 0] = x0 * inv; wk[m * 3 + 1] = x1 * inv; wk[m * 3 + 2] = x2 * inv;
        if (m == 0) {
            float s0 = slog[0], s1 = slog[1], s2 = slog[2];
            float mx2 = fmaxf(s0, fmaxf(s1, s2));
            float e0b = expf(s0 - mx2), e1b = expf(s1 - mx2), e2b = expf(s2 - mx2);
            float inv2 = 3.f / (e0b + e1b + e2b);
            sw[0] = e0b * inv2; sw[1] = e1b * inv2; sw[2] = e2b * inv2;
        }
    }
}

// ---------------- prep: w2ot[o][c^((o&7)<<3)] = sum_h w_ch[o,h]*pw_w[h,c] (bf16) ----------------
__global__ __launch_bounds__(256) void prep_w2(const float* __restrict__ w_ch,
        const float* __restrict__ pw_w, const float* __restrict__ pw_b,
        unsigned short* __restrict__ w2ot, float* __restrict__ pbs) {
    int tid = threadIdx.x;
    if (blockIdx.x == 64) {
        if (tid < 128) {
            float pb = 0.f, s = 0.f;
            for (int h = 0; h < HID; h++) {
                float w = w_ch[tid * HID + h];
                pb += w * pw_b[h]; s += w;
            }
            pbs[tid] = pb; pbs[128 + tid] = s;
        }
        return;
    }
    int idx = blockIdx.x * 256 + tid;
    int c = idx >> 7, o = idx & 127;
    float acc = 0.f;
    for (int h = 0; h < HID; h++) acc += w_ch[o * HID + h] * pw_w[h * CIN + c];
    w2ot[o * 128 + (c ^ ((o & 7) << 3))] = f2bf(acc);
}

// ---------------- prep: w_t -> bf16 + row sums ----------------
__global__ __launch_bounds__(256) void prep_wt(const float* __restrict__ wt0,
        const float* __restrict__ wt1, const float* __restrict__ wt2,
        unsigned short* __restrict__ wtb, float* __restrict__ wsum) {
    int wid = blockIdx.x * 4 + (threadIdx.x >> 6);
    int lane = threadIdx.x & 63;
    const float* src; int T, p, m; size_t off;
    if (wid < 192)      { m = 0; p = wid;       src = wt0; T = 1024; off = 0; }
    else if (wid < 384) { m = 1; p = wid - 192; src = wt1; T = 512;  off = (size_t)192 * 1024; }
    else                { m = 2; p = wid - 384; src = wt2; T = 256;  off = (size_t)192 * 1024 + (size_t)192 * 512; }
    const float* row = src + (size_t)p * T;
    unsigned short* dst = wtb + off + (size_t)p * T;
    float s = 0.f;
    for (int j = lane; j < T; j += 64) { float v = row[j]; s += v; dst[j] = f2bf(v); }
#pragma unroll
    for (int d = 1; d < 64; d <<= 1) s += __shfl_xor(s, d);
    if (lane == 0) wsum[m * 192 + p] = s;
}

// ---------------- depthwise mix: one wave per channel, pair-ILP, masked taps ----------------
template<int T>
__global__ __launch_bounds__(256) void dwmix_k(const float* __restrict__ xm,
        const float* __restrict__ dw_w, const float* __restrict__ dw_b,
        const int* __restrict__ freqs, const float* __restrict__ wkbuf, int m,
        unsigned short* __restrict__ dwmix) {
    constexpr int CPB = 4;
    constexpr int RS  = T + 8;
    constexpr int NP  = T / 128;
    __shared__ float xs[CPB * RS];
    __shared__ unsigned short msk[3 * T];
    int tid = threadIdx.x;
    int b = blockIdx.y;
    int c0 = blockIdx.x * CPB;

    int pk[3]; float wkv[3];
#pragma unroll
    for (int k = 0; k < 3; k++) {
        int f = freqs[m * 3 + k];
        pk[k] = T / f;
        wkv[k] = wkbuf[m * 3 + k];
    }
    const float* src = xm + ((size_t)b * CIN + c0) * T;
    for (int i = tid; i < CPB * (T / 4); i += 256) {
        int ch = i / (T / 4), seg = i - ch * (T / 4);
        *(float4*)&xs[ch * RS + seg * 4] = *(const float4*)&src[(size_t)ch * T + seg * 4];
    }
    if (tid < CPB) xs[tid * RS + T] = 0.f;
    for (int l = tid; l < T; l += 256) {
#pragma unroll
        for (int k = 0; k < 3; k++) {
            int p = pk[k];
            int rows = (T + p - 1) / p;
            int r = l / p, cc = l - r * p;
            unsigned mm = 0; int q = 0;
#pragma unroll
            for (int dr = -1; dr <= 1; dr++)
#pragma unroll
                for (int dc = -1; dc <= 1; dc++, q++) {
                    int rr2 = r + dr, c2 = cc + dc;
                    int pos = l + dr * p + dc;
                    if (rr2 >= 0 && rr2 < rows && c2 >= 0 && c2 < p && pos < T)
                        mm |= 1u << q;
                }
            msk[k * T + l] = (unsigned short)mm;
        }
    }
    __syncthreads();

    int ch = tid >> 6, j = tid & 63;
    int c = c0 + ch;
    float w9[9];
#pragma unroll
    for (int q = 0; q < 9; q++) w9[q] = dw_w[c * 9 + q];
    float bias = dw_b[c];
    int cb = ch * RS;
    unsigned short* outp = dwmix + ((size_t)b * CIN + c) * T;

    for (int i = 0; i < NP; i++) {
        int l0 = i * 128 + 2 * j, l1 = l0 + 1;
        float s0 = bias, s1 = bias;
#pragma unroll
        for (int k = 0; k < 3; k++) {
            int p = pk[k];
            unsigned m0 = msk[k * T + l0];
            unsigned m1 = msk[k * T + l1];
            float a0 = 0.f, a1 = 0.f;
            int q = 0;
#pragma unroll
            for (int dr = -1; dr <= 1; dr++) {
                int r0 = l0 + dr * p, r1 = l1 + dr * p;
#pragma unroll
                for (int dc = -1; dc <= 1; dc++, q++) {
                    int i0 = ((m0 >> q) & 1) ? (r0 + dc) : T;
                    int i1 = ((m1 >> q) & 1) ? (r1 + dc) : T;
                    a0 += w9[q] * xs[cb + i0];
                    a1 += w9[q] * xs[cb + i1];
                }
            }
            s0 += wkv[k] * a0; s1 += wkv[k] * a1;
        }
        unsigned pk2 = (unsigned)f2bf(s0) | ((unsigned)f2bf(s1) << 16);
        *(unsigned*)&outp[l0] = pk2;
    }
}

// ---------------- tp GEMM: C[192][8192] = A[192][T] * B[8192][T]^T (bf16 MFMA) ----------------
template<int T>
__global__ __launch_bounds__(256) void tp_gemm(const unsigned short* __restrict__ A,
        const unsigned short* __restrict__ B, unsigned short* __restrict__ C) {
    __shared__ __align__(16) unsigned short As[64 * 72];
    __shared__ __align__(16) unsigned short Bs[64 * 72];
    int tid = threadIdx.x;
    int lane = tid & 63, wave = tid >> 6;
    int wm = (wave >> 1) * 32, wn = (wave & 1) * 32;
    int p0 = blockIdx.x * 64, n0 = blockIdx.y * 64;
    f32x4 acc[2][2];
#pragma unroll
    for (int i = 0; i < 2; i++)
#pragma unroll
        for (int j = 0; j < 2; j++) acc[i][j] = (f32x4){0.f, 0.f, 0.f, 0.f};

    int r = tid >> 2, seg = tid & 3;
    const unsigned short* ga = A + (size_t)(p0 + r) * T + seg * 16;
    const unsigned short* gb = B + (size_t)(n0 + r) * T + seg * 16;
    unsigned short* la = &As[r * 72 + seg * 16];
    unsigned short* lb = &Bs[r * 72 + seg * 16];
    int fr = lane & 15, fk = (lane >> 4) * 8;

    for (int k0 = 0; k0 < T; k0 += 64) {
        __syncthreads();
        *(uint4*)la       = *(const uint4*)ga;
        *(uint4*)(la + 8) = *(const uint4*)(ga + 8);
        *(uint4*)lb       = *(const uint4*)gb;
        *(uint4*)(lb + 8) = *(const uint4*)(gb + 8);
        ga += 64; gb += 64;
        __syncthreads();
#pragma unroll
        for (int ks = 0; ks < 2; ks++) {
            int ko = ks * 32 + fk;
            s16x8 a0 = *(const s16x8*)&As[(wm + fr) * 72 + ko];
            s16x8 a1 = *(const s16x8*)&As[(wm + 16 + fr) * 72 + ko];
            s16x8 b0 = *(const s16x8*)&Bs[(wn + fr) * 72 + ko];
            s16x8 b1 = *(const s16x8*)&Bs[(wn + 16 + fr) * 72 + ko];
            acc[0][0] = __builtin_amdgcn_mfma_f32_16x16x32_bf16(a0, b0, acc[0][0], 0, 0, 0);
            acc[0][1] = __builtin_amdgcn_mfma_f32_16x16x32_bf16(a0, b1, acc[0][1], 0, 0, 0);
            acc[1][0] = __builtin_amdgcn_mfma_f32_16x16x32_bf16(a1, b0, acc[1][0], 0, 0, 0);
            acc[1][1] = __builtin_amdgcn_mfma_f32_16x16x32_bf16(a1, b1, acc[1][1], 0, 0, 0);
        }
    }
    int crow = (lane >> 4) * 4, ccol = lane & 15;
#pragma unroll
    for (int i = 0; i < 2; i++)
#pragma unroll
        for (int j = 0; j < 2; j++) {
            int col = n0 + wn + j * 16 + ccol;
#pragma unroll
            for (int reg = 0; reg < 4; reg++) {
                int row = p0 + wm + i * 16 + crow + reg;
                C[(size_t)row * 8192 + col] = f2bf(acc[i][j][reg]);
            }
        }
}

// ---------------- final: out = residual + sum_m sw_m*(W2@tp_m + biases) ----------------
__global__ __launch_bounds__(256) void final_out(const float* __restrict__ x,
        const unsigned short* __restrict__ tp, const unsigned short* __restrict__ w2ot,
        const float* __restrict__ pbs, const float* __restrict__ wsum,
        const float* __restrict__ bt0, const float* __restrict__ bt1,
        const float* __restrict__ bt2, const float* __restrict__ b_ch,
        const float* __restrict__ swb, float* __restrict__ out) {
    __shared__ unsigned short w2s[128 * 128];
    __shared__ float tpsS[32][128];
    __shared__ float wsS[32], btS[32];
    const size_t TPPL = (size_t)192 * 8192;
    int tid = threadIdx.x;
    int r0 = blockIdx.x * 32;
    float sw0 = swb[0], sw1 = swb[1], sw2 = swb[2];

#pragma unroll
    for (int i = 0; i < 8; i++)
        ((uint4*)w2s)[i * 256 + tid] = ((const uint4*)w2ot)[i * 256 + tid];
#pragma unroll
    for (int it = 0; it < 2; it++) {
        int idx = tid + it * 256;
        int rr = idx >> 4, u = idx & 15;
        int r = r0 + rr;
        int b2 = r / 192, p2 = r - b2 * 192;
        size_t base = (size_t)p2 * 8192 + (size_t)b2 * 128 + u * 8;
        uint4 q0 = *(const uint4*)&tp[base];
        uint4 q1 = *(const uint4*)&tp[TPPL + base];
        uint4 q2 = *(const uint4*)&tp[2 * TPPL + base];
        const unsigned* a0 = (const unsigned*)&q0;
        const unsigned* a1 = (const unsigned*)&q1;
        const unsigned* a2 = (const unsigned*)&q2;
        float o8[8];
#pragma unroll
        for (int w = 0; w < 4; w++) {
            o8[2 * w]     = sw0 * bf2f(a0[w] & 0xffff) + sw1 * bf2f(a1[w] & 0xffff)
                          + sw2 * bf2f(a2[w] & 0xffff);
            o8[2 * w + 1] = sw0 * bf2f(a0[w] >> 16) + sw1 * bf2f(a1[w] >> 16)
                          + sw2 * bf2f(a2[w] >> 16);
        }
        *(float4*)&tpsS[rr][u * 8]     = *(float4*)&o8[0];
        *(float4*)&tpsS[rr][u * 8 + 4] = *(float4*)&o8[4];
    }
    if (tid < 32) {
        int r = r0 + tid;
        int b2 = r / 192, p = r - b2 * 192;
        wsS[tid] = sw0 * wsum[p] + sw1 * wsum[192 + p] + sw2 * wsum[384 + p];
        btS[tid] = sw0 * bt0[p] + sw1 * bt1[p] + sw2 * bt2[p];
    }
    __syncthreads();

    int o = tid & 127, half = tid >> 7;
    int rbase = half * 16;
    float pbv  = pbs[o];
    float schv = pbs[128 + o];
    float bchv = (sw0 + sw1 + sw2) * b_ch[o];
    float acc[16];
#pragma unroll
    for (int rr = 0; rr < 16; rr++) acc[rr] = 0.f;

#pragma unroll 2
    for (int cb8 = 0; cb8 < 16; cb8++) {
        uint4 wv = *(const uint4*)&w2s[o * 128 + ((cb8 ^ (o & 7)) << 3)];
        const unsigned* aw = (const unsigned*)&wv;
        float wf[8];
#pragma unroll
        for (int w = 0; w < 4; w++) {
            wf[2 * w]     = bf2f(aw[w] & 0xffff);
            wf[2 * w + 1] = bf2f(aw[w] >> 16);
        }
        int cc = cb8 * 8;
#pragma unroll
        for (int rr = 0; rr < 16; rr++) {
            const float* tr = &tpsS[rbase + rr][cc];
            float4 t0 = *(const float4*)tr;
            float4 t1 = *(const float4*)(tr + 4);
            acc[rr] += wf[0] * t0.x + wf[1] * t0.y + wf[2] * t0.z + wf[3] * t0.w
                     + wf[4] * t1.x + wf[5] * t1.y + wf[6] * t1.z + wf[7] * t1.w;
        }
    }
#pragma unroll
    for (int rr = 0; rr < 16; rr++) {
        int r = r0 + rbase + rr;
        int b2 = r / 192, p = r - b2 * 192;
        float res = x[((size_t)b2 * T0 + (T0 - PRED) + p) * CIN + o];
        out[(size_t)r * TGT + o] = res + acc[rr] + pbv * wsS[rbase + rr]
                                 + schv * btS[rbase + rr] + bchv;
    }
}

extern "C" void kernel_launch(void* const* d_in, const int* in_sizes, int n_in,
                              void* d_out, int out_size, void* d_ws, size_t ws_size,
                              hipStream_t stream) {
    const float* x    = (const float*)d_in[0];
    const float* dw_w = (const float*)d_in[1];
    const float* dw_b = (const float*)d_in[2];
    const float* pw_w = (const float*)d_in[3];
    const float* pw_b = (const float*)d_in[4];
    const float* wt0  = (const float*)d_in[5];
    const float* bt0  = (const float*)d_in[6];
    const float* wt1  = (const float*)d_in[7];
    const float* bt1  = (const float*)d_in[8];
    const float* wt2  = (const float*)d_in[9];
    const float* bt2  = (const float*)d_in[10];
    const float* w_ch = (const float*)d_in[11];
    const float* b_ch = (const float*)d_in[12];
    const float* slog = (const float*)d_in[13];
    float* out = (float*)d_out;
    float* ws  = (float*)d_ws;

    float* xct    = ws + XCT_OFF;
    float* s1b    = ws + S1_OFF;
    float* s2b    = ws + S2_OFF;
    float* parts  = ws + P0_OFF;
    float* parts2 = ws + PARTS2_OFF;
    int*   freqs  = (int*)(ws + META_OFF);
    float* wkb    = ws + META_OFF + 16;
    float* swb    = ws + META_OFF + 32;
    unsigned short* w2tb = (unsigned short*)(ws + W2T_OFF);
    float* pbs    = ws + PBS_OFF;
    float* wsumb  = ws + WSUM_OFF;
    unsigned short* wtb  = (unsigned short*)(ws + WTB_OFF);
    unsigned short* dwm  = (unsigned short*)(ws + DWMIX_OFF);
    unsigned short* tpb  = (unsigned short*)(ws + TP_OFF);

    const size_t WT1O = (size_t)192 * 1024;
    const size_t WT2O = WT1O + (size_t)192 * 512;
    const size_t TPPL = (size_t)192 * 8192;

    front<<<dim3(32, 4, NB), dim3(32, 8, 1), 0, stream>>>(x, xct, s1b, s2b);

    fft_amps<10><<<1024, 256, 0, stream>>>(xct, parts, 520);
    fft_amps<9><<<1024, 256, 0, stream>>>(s1b, parts + (size_t)1024 * 520, 264);
    fft_amps<8><<<1024, 256, 0, stream>>>(s2b, parts + (size_t)1024 * 520 + (size_t)1024 * 264, 136);
    reduce_partA<<<dim3(9, 3, 16), 256, 0, stream>>>(parts, parts2);
    meta_topk<<<3, 256, 0, stream>>>(parts2, slog, freqs, wkb, swb);

    prep_w2<<<65, 256, 0, stream>>>(w_ch, pw_w, pw_b, w2tb, pbs);
    prep_wt<<<144, 256, 0, stream>>>(wt0, wt1, wt2, wtb, wsumb);

    // scale 0 (T=1024)
    dwmix_k<1024><<<dim3(32, NB), 256, 0, stream>>>(xct, dw_w, dw_b, freqs, wkb, 0, dwm);
    tp_gemm<1024><<<dim3(3, 128), 256, 0, stream>>>(wtb, dwm, tpb);
    // scale 1 (T=512)
    dwmix_k<512><<<dim3(32, NB), 256, 0, stream>>>(s1b, dw_w, dw_b, freqs, wkb, 1, dwm);
    tp_gemm<512><<<dim3(3, 128), 256, 0, stream>>>(wtb + WT1O, dwm, tpb + TPPL);
    // scale 2 (T=256)
    dwmix_k<256><<<dim3(32, NB), 256, 0, stream>>>(s2b, dw_w, dw_b, freqs, wkb, 2, dwm);
    tp_gemm<256><<<dim3(3, 128), 256, 0, stream>>>(wtb + WT2O, dwm, tpb + 2 * TPPL);

    final_out<<<384, 256, 0, stream>>>(x, tpb, w2tb, pbs, wsumb,
                                       bt0, bt1, bt2, b_ch, swb, out);
}